// Round 1
// baseline (445.348 us; speedup 1.0000x reference)
//
#include <hip/hip_runtime.h>
#include <stdint.h>

// Problem constants (B=4, C=32, H=W=32, HEADS=4, DIM_HEAD=32)
#define HID 4096   // hidden = C*HEADS*DIM_HEAD
#define NSP 1024   // H*W
#define CIN 32
// Requires ws_size >= 151,519,744 bytes (~145 MiB)

typedef unsigned short u16;
typedef float f32x4 __attribute__((ext_vector_type(4)));
typedef _Float16 f16;
typedef _Float16 f16x8 __attribute__((ext_vector_type(8)));
typedef _Float16 h4 __attribute__((ext_vector_type(4)));
typedef unsigned short u16x4 __attribute__((ext_vector_type(4)));
typedef unsigned short u16x8 __attribute__((ext_vector_type(8)));

__device__ __forceinline__ u16 f2h(float f) {
  return __builtin_bit_cast(u16, (f16)f);
}
__device__ __forceinline__ float h2f(u16 u) {
  return (float)__builtin_bit_cast(f16, u);
}

__device__ __forceinline__ void gload16(const u16* g, u16* l) {
  __builtin_amdgcn_global_load_lds(
      (const __attribute__((address_space(1))) void*)g,
      (__attribute__((address_space(3))) void*)l, 16, 0, 0);
}

// ---------------------------------------------------------------------------
// K1: V = 1x1conv(image) for channels [2*HID, 3*HID), stored fp16 as
// v[(b*4+hh)*1024 + e][n], where channel ch = e*4 + hh.
// 32 rows/block, 2 rows/thread, image chunk staged in LDS.
// ---------------------------------------------------------------------------
__global__ __launch_bounds__(256) void conv_v(const float* __restrict__ img,
    const float* __restrict__ wq, const float* __restrict__ bq,
    u16* __restrict__ v) {
  __shared__ __align__(16) float imgS[CIN * 64];
  int t = threadIdx.x;
  int R0 = blockIdx.x * 32;
  int b = R0 >> 12; int ch0 = R0 & 4095;
  int slot = t >> 4, g = t & 15;
  int chA = ch0 + slot * 2, chB = chA + 1;
  float wr0[CIN], wr1[CIN];
#pragma unroll
  for (int c = 0; c < CIN; c++) {
    wr0[c] = wq[(size_t)(2 * HID + chA) * CIN + c];
    wr1[c] = wq[(size_t)(2 * HID + chB) * CIN + c];
  }
  float bias0 = bq[2 * HID + chA], bias1 = bq[2 * HID + chB];
  size_t row0 = ((size_t)(b * 4 + (chA & 3)) * 1024 + (chA >> 2)) * NSP;
  size_t row1 = ((size_t)(b * 4 + (chB & 3)) * 1024 + (chB >> 2)) * NSP;
  for (int chunk = 0; chunk < 16; chunk++) {
    __syncthreads();
    for (int i = t; i < CIN * 64; i += 256)
      imgS[i] = img[((size_t)b * CIN + (i >> 6)) * NSP + chunk * 64 + (i & 63)];
    __syncthreads();
    f32x4 a0 = {0.f, 0.f, 0.f, 0.f}, a1 = {0.f, 0.f, 0.f, 0.f};
#pragma unroll
    for (int c = 0; c < CIN; c++) {
      f32x4 x = *(const f32x4*)&imgS[c * 64 + g * 4];
      a0 += wr0[c] * x;
      a1 += wr1[c] * x;
    }
    u16x4 o0, o1;
#pragma unroll
    for (int j = 0; j < 4; j++) {
      o0[j] = f2h(a0[j] + bias0);
      o1[j] = f2h(a1[j] + bias1);
    }
    *(u16x4*)&v[row0 + chunk * 64 + g * 4] = o0;
    *(u16x4*)&v[row1 + chunk * 64 + g * 4] = o1;
  }
}

// ---------------------------------------------------------------------------
// K2: K = softmax over n of 1x1conv(image) channels [HID, 2*HID).
// Logits computed in fp32 on the fly (no materialization). No max-sub needed
// (|logit| <~ 6). exp kept as fp16 in regs, rescaled by 1/sum, stored fp16.
// ---------------------------------------------------------------------------
__global__ __launch_bounds__(256) void conv_ksm(const float* __restrict__ img,
    const float* __restrict__ wq, const float* __restrict__ bq,
    u16* __restrict__ kout) {
  __shared__ __align__(16) float imgS[CIN * 64];
  __shared__ float sred[32][17];
  __shared__ float sinv[32];
  int t = threadIdx.x;
  int R0 = blockIdx.x * 32;
  int b = R0 >> 12; int ch0 = R0 & 4095;
  int slot = t >> 4, g = t & 15;
  int chA = ch0 + slot * 2, chB = chA + 1;
  float wr0[CIN], wr1[CIN];
#pragma unroll
  for (int c = 0; c < CIN; c++) {
    wr0[c] = wq[(size_t)(HID + chA) * CIN + c];
    wr1[c] = wq[(size_t)(HID + chB) * CIN + c];
  }
  float bias0 = bq[HID + chA], bias1 = bq[HID + chB];
  h4 e0[16], e1[16];
  float s0 = 0.f, s1 = 0.f;
#pragma unroll
  for (int chunk = 0; chunk < 16; chunk++) {
    __syncthreads();
    for (int i = t; i < CIN * 64; i += 256)
      imgS[i] = img[((size_t)b * CIN + (i >> 6)) * NSP + chunk * 64 + (i & 63)];
    __syncthreads();
    f32x4 a0 = {0.f, 0.f, 0.f, 0.f}, a1 = {0.f, 0.f, 0.f, 0.f};
#pragma unroll
    for (int c = 0; c < CIN; c++) {
      f32x4 x = *(const f32x4*)&imgS[c * 64 + g * 4];
      a0 += wr0[c] * x;
      a1 += wr1[c] * x;
    }
#pragma unroll
    for (int j = 0; j < 4; j++) {
      float v0 = __expf(a0[j] + bias0), v1 = __expf(a1[j] + bias1);
      s0 += v0; s1 += v1;
      e0[chunk][j] = (f16)v0;
      e1[chunk][j] = (f16)v1;
    }
  }
  sred[slot * 2 + 0][g] = s0;
  sred[slot * 2 + 1][g] = s1;
  __syncthreads();
  if (t < 32) {
    float s = 0.f;
#pragma unroll
    for (int gg = 0; gg < 16; gg++) s += sred[t][gg];
    sinv[t] = 1.0f / s;
  }
  __syncthreads();
  float i0 = sinv[slot * 2 + 0], i1 = sinv[slot * 2 + 1];
  size_t row0 = ((size_t)(b * 4 + (chA & 3)) * 1024 + (chA >> 2)) * NSP;
  size_t row1 = ((size_t)(b * 4 + (chB & 3)) * 1024 + (chB >> 2)) * NSP;
#pragma unroll
  for (int chunk = 0; chunk < 16; chunk++) {
    u16x4 o0, o1;
#pragma unroll
    for (int j = 0; j < 4; j++) {
      o0[j] = f2h((float)e0[chunk][j] * i0);
      o1[j] = f2h((float)e1[chunk][j] * i1);
    }
    *(u16x4*)&kout[row0 + chunk * 64 + g * 4] = o0;
    *(u16x4*)&kout[row1 + chunk * 64 + g * 4] = o1;
  }
}

// ---------------------------------------------------------------------------
// K3: Q = softmax over d (feature dim) * scale, written TRANSPOSED:
// qt[(b*4+hh)*1M + n*1024 + d], fp16. Block = (b, hh, 64 n's). Image columns
// cached in registers; w_qkv staged per 128-d chunk. Pass B writes
// unnormalized exp (fp16) + accumulates sums; pass C rescales in place.
// ---------------------------------------------------------------------------
__global__ __launch_bounds__(256) void conv_qsm(const float* __restrict__ img,
    const float* __restrict__ wq, const float* __restrict__ bq,
    u16* __restrict__ qt) {
  __shared__ __align__(16) float wS[128 * 36];
  __shared__ float bS[128];
  __shared__ float sred[8][65];
  __shared__ float sinvS[64];
  int t = threadIdx.x;
  int n0 = blockIdx.x * 64;
  int hh = blockIdx.y, b = blockIdx.z;
  int dq = t >> 5, nl = t & 31;
  int n_a = n0 + nl * 2, n_b = n_a + 1;
  f32x4 ia[8], ib[8];
#pragma unroll
  for (int cg = 0; cg < 8; cg++) {
    f32x4 ta, tb;
#pragma unroll
    for (int j = 0; j < 4; j++) {
      ta[j] = img[((size_t)b * CIN + cg * 4 + j) * NSP + n_a];
      tb[j] = img[((size_t)b * CIN + cg * 4 + j) * NSP + n_b];
    }
    ia[cg] = ta; ib[cg] = tb;
  }
  size_t qtbase = (size_t)(b * 4 + hh) * 1024 * 1024;
  float sa = 0.f, sb = 0.f;
  for (int chunk = 0; chunk < 8; chunk++) {
    __syncthreads();
    for (int i = t; i < 128 * 32; i += 256) {
      int dl = i >> 5, c = i & 31;
      wS[dl * 36 + c] = wq[((size_t)(chunk * 128 + dl) * 4 + hh) * CIN + c];
    }
    if (t < 128) bS[t] = bq[(size_t)(chunk * 128 + t) * 4 + hh];
    __syncthreads();
    u16x8 pa0, pa1, pb0, pb1;
#pragma unroll
    for (int i = 0; i < 16; i++) {
      int dl = dq * 16 + i;
      const f32x4* wv = (const f32x4*)&wS[dl * 36];
      f32x4 aa = {0.f, 0.f, 0.f, 0.f}, ab = {0.f, 0.f, 0.f, 0.f};
#pragma unroll
      for (int cg = 0; cg < 8; cg++) {
        f32x4 w4 = wv[cg];
        aa += w4 * ia[cg];
        ab += w4 * ib[cg];
      }
      float la = aa[0] + aa[1] + aa[2] + aa[3] + bS[dl];
      float lb = ab[0] + ab[1] + ab[2] + ab[3] + bS[dl];
      float ea = __expf(la), eb = __expf(lb);
      sa += ea; sb += eb;
      u16 ha = __builtin_bit_cast(u16, (f16)ea);
      u16 hb = __builtin_bit_cast(u16, (f16)eb);
      if (i < 8) { pa0[i & 7] = ha; pb0[i & 7] = hb; }
      else       { pa1[i & 7] = ha; pb1[i & 7] = hb; }
    }
    size_t da = qtbase + (size_t)n_a * 1024 + chunk * 128 + dq * 16;
    size_t db = qtbase + (size_t)n_b * 1024 + chunk * 128 + dq * 16;
    *(u16x8*)&qt[da + 0] = pa0;
    *(u16x8*)&qt[da + 8] = pa1;
    *(u16x8*)&qt[db + 0] = pb0;
    *(u16x8*)&qt[db + 8] = pb1;
  }
  sred[dq][nl * 2 + 0] = sa;
  sred[dq][nl * 2 + 1] = sb;
  __syncthreads();
  if (t < 64) {
    float s = 0.f;
#pragma unroll
    for (int q = 0; q < 8; q++) s += sred[q][t];
    sinvS[t] = 0.17677669529663687f / s;  // scale = DIM_HEAD^-0.5
  }
  __syncthreads();
  float iva = sinvS[nl * 2 + 0], ivb = sinvS[nl * 2 + 1];
  for (int chunk = 0; chunk < 8; chunk++) {
    size_t da = qtbase + (size_t)n_a * 1024 + chunk * 128 + dq * 16;
    size_t db = qtbase + (size_t)n_b * 1024 + chunk * 128 + dq * 16;
#pragma unroll
    for (int hf = 0; hf < 2; hf++) {
      u16x8 pa = *(u16x8*)&qt[da + hf * 8];
      u16x8 pb = *(u16x8*)&qt[db + hf * 8];
      u16x8 oa, ob;
#pragma unroll
      for (int j = 0; j < 8; j++) {
        oa[j] = f2h(h2f(pa[j]) * iva);
        ob[j] = f2h(h2f(pb[j]) * ivb);
      }
      *(u16x8*)&qt[da + hf * 8] = oa;
      *(u16x8*)&qt[db + hf * 8] = ob;
    }
  }
}

// ---------------------------------------------------------------------------
// K4/K5: batched C = A * B^T, M=N=K=1024, 16 batches (z = b*4+hh), fp16 in,
// fp32 accum. 128x128 tile, BK=64, 4 waves of 64x64, global_load_lds staging.
// mfma_f32_16x16x32_f16; C/D: col=lane&15, row=(lane>>4)*4+reg (verified map).
// CT=u16 -> store fp16; CT=float -> store fp32.
// ---------------------------------------------------------------------------
template <typename CT>
__global__ __launch_bounds__(256) void gemm_bt(const u16* __restrict__ A0,
    const u16* __restrict__ B0, CT* __restrict__ C0) {
  __shared__ __align__(16) u16 As[128 * 64];
  __shared__ __align__(16) u16 Bs[128 * 64];
  int t = threadIdx.x;
  int w = t >> 6, l = t & 63;
  int z = blockIdx.z;
  const u16* A = A0 + (size_t)z * (1024 * 1024) + (size_t)blockIdx.y * 128 * 1024;
  const u16* Bt = B0 + (size_t)z * (1024 * 1024) + (size_t)blockIdx.x * 128 * 1024;
  int wr = w >> 1, wc = w & 1;
  f32x4 acc[4][4];
#pragma unroll
  for (int m = 0; m < 4; m++)
#pragma unroll
    for (int n = 0; n < 4; n++) {
      f32x4 zz = {0.f, 0.f, 0.f, 0.f};
      acc[m][n] = zz;
    }
  int srow = l >> 3, scol = (l & 7) * 8;
  for (int kt = 0; kt < 16; kt++) {
    int k0 = kt * 64;
#pragma unroll
    for (int s = 0; s < 4; s++) {
      int strip = w * 4 + s;
      int r = strip * 8 + srow;
      gload16(A + (size_t)r * 1024 + k0 + scol, &As[strip * 512]);
      gload16(Bt + (size_t)r * 1024 + k0 + scol, &Bs[strip * 512]);
    }
    __syncthreads();
#pragma unroll
    for (int kk = 0; kk < 2; kk++) {
      f16x8 a[4], bb[4];
#pragma unroll
      for (int m = 0; m < 4; m++)
        a[m] = *(const f16x8*)&As[(wr * 64 + m * 16 + (l & 15)) * 64 + kk * 32 + (l >> 4) * 8];
#pragma unroll
      for (int n = 0; n < 4; n++)
        bb[n] = *(const f16x8*)&Bs[(wc * 64 + n * 16 + (l & 15)) * 64 + kk * 32 + (l >> 4) * 8];
#pragma unroll
      for (int m = 0; m < 4; m++)
#pragma unroll
        for (int n = 0; n < 4; n++)
          acc[m][n] = __builtin_amdgcn_mfma_f32_16x16x32_f16(a[m], bb[n], acc[m][n], 0, 0, 0);
    }
    __syncthreads();
  }
  CT* Cp = C0 + (size_t)z * (1024 * 1024);
  int rbase = blockIdx.y * 128 + wr * 64 + (l >> 4) * 4;
  int cbase = blockIdx.x * 128 + wc * 64 + (l & 15);
#pragma unroll
  for (int m = 0; m < 4; m++)
#pragma unroll
    for (int n = 0; n < 4; n++)
#pragma unroll
      for (int j = 0; j < 4; j++) {
        int r = rbase + m * 16 + j;
        int cc = cbase + n * 16;
        float val = acc[m][n][j];
        if constexpr (sizeof(CT) == 2) {
          Cp[(size_t)r * 1024 + cc] = f2h(val);
        } else {
          Cp[(size_t)r * 1024 + cc] = val;
        }
      }
}

// ---------------------------------------------------------------------------
// K6: out-proj partials. final[b][o][n] = sum_c att[b][c][n]*w_out[o][c].
// K split into 32 chunks of 128; block = (kc, og(16 o's), b); thread = 4 n's.
// ---------------------------------------------------------------------------
__global__ __launch_bounds__(256) void oproj(const float* __restrict__ att,
    const float* __restrict__ wout, float* __restrict__ partial) {
  __shared__ __align__(16) float wS[128 * 20];
  int t = threadIdx.x;
  int kc = blockIdx.x, og = blockIdx.y, b = blockIdx.z;
  for (int i = t; i < 128 * 16; i += 256) {
    int cc = i & 127, oo = i >> 7;
    wS[cc * 20 + oo] = wout[(size_t)(og * 16 + oo) * HID + kc * 128 + cc];
  }
  __syncthreads();
  f32x4 acc[16];
#pragma unroll
  for (int o = 0; o < 16; o++) {
    f32x4 zz = {0.f, 0.f, 0.f, 0.f};
    acc[o] = zz;
  }
  const float* X = att + ((size_t)b * HID + kc * 128) * NSP + t * 4;
#pragma unroll 4
  for (int cc = 0; cc < 128; cc++) {
    f32x4 x = *(const f32x4*)(X + (size_t)cc * NSP);
    const f32x4* wv = (const f32x4*)&wS[cc * 20];
#pragma unroll
    for (int g = 0; g < 4; g++) {
      f32x4 w4 = wv[g];
      acc[g * 4 + 0] += w4[0] * x;
      acc[g * 4 + 1] += w4[1] * x;
      acc[g * 4 + 2] += w4[2] * x;
      acc[g * 4 + 3] += w4[3] * x;
    }
  }
#pragma unroll
  for (int o = 0; o < 16; o++)
    *(f32x4*)&partial[(((size_t)b * 32 + kc) * 32 + og * 16 + o) * NSP + t * 4] = acc[o];
}

// ---------------------------------------------------------------------------
// K7a: reduce partials over kc, add bias, write pre-GN fp32 + per-block
// (sum, sumsq) stats. Block = (nc: 64 n's, b); thread = (nl, oq: 8 o's).
// ---------------------------------------------------------------------------
__global__ __launch_bounds__(256) void reduce_stats(const float* __restrict__ partial,
    const float* __restrict__ bout, float* __restrict__ fin,
    float* __restrict__ stats) {
  int t = threadIdx.x;
  int nc = blockIdx.x, b = blockIdx.y;
  int nl = t & 63, oq = t >> 6;
  int n = nc * 64 + nl;
  float s1 = 0.f, s2 = 0.f;
#pragma unroll
  for (int oo = 0; oo < 8; oo++) {
    int o = oq * 8 + oo;
    float s = bout[o];
#pragma unroll
    for (int kc = 0; kc < 32; kc++)
      s += partial[(((size_t)b * 32 + kc) * 32 + o) * NSP + n];
    fin[((size_t)b * 32 + o) * NSP + n] = s;
    s1 += s; s2 += s * s;
  }
#pragma unroll
  for (int off = 32; off > 0; off >>= 1) {
    s1 += __shfl_xor(s1, off);
    s2 += __shfl_xor(s2, off);
  }
  __shared__ float r1[4], r2[4];
  int wid = t >> 6;
  if ((t & 63) == 0) { r1[wid] = s1; r2[wid] = s2; }
  __syncthreads();
  if (t == 0) {
    stats[((size_t)b * 16 + nc) * 2 + 0] = r1[0] + r1[1] + r1[2] + r1[3];
    stats[((size_t)b * 16 + nc) * 2 + 1] = r2[0] + r2[1] + r2[2] + r2[3];
  }
}

// ---------------------------------------------------------------------------
// K7b: GroupNorm(1, C) per batch: combine stats, normalize, affine, write out.
// ---------------------------------------------------------------------------
__global__ __launch_bounds__(256) void gn_norm(const float* __restrict__ fin,
    const float* __restrict__ stats, const float* __restrict__ gamma,
    const float* __restrict__ beta, float* __restrict__ out) {
  int t = threadIdx.x;
  int nc = blockIdx.x, b = blockIdx.y;
  float s1 = 0.f, s2 = 0.f;
#pragma unroll
  for (int i = 0; i < 16; i++) {
    s1 += stats[((size_t)b * 16 + i) * 2 + 0];
    s2 += stats[((size_t)b * 16 + i) * 2 + 1];
  }
  const float inv_n = 1.0f / 32768.0f;
  float mean = s1 * inv_n;
  float var = s2 * inv_n - mean * mean;
  float rstd = rsqrtf(var + 1e-5f);
  int nl = t & 63, oq = t >> 6;
  int n = nc * 64 + nl;
#pragma unroll
  for (int oo = 0; oo < 8; oo++) {
    int o = oq * 8 + oo;
    float v = fin[((size_t)b * 32 + o) * NSP + n];
    out[((size_t)b * 32 + o) * NSP + n] = (v - mean) * rstd * gamma[o] + beta[o];
  }
}

// ---------------------------------------------------------------------------
extern "C" void kernel_launch(void* const* d_in, const int* in_sizes, int n_in,
                              void* d_out, int out_size, void* d_ws, size_t ws_size,
                              hipStream_t stream) {
  (void)in_sizes; (void)n_in; (void)out_size; (void)ws_size;
  const float* img   = (const float*)d_in[0];
  const float* wqkv  = (const float*)d_in[1];
  const float* bqkv  = (const float*)d_in[2];
  const float* wout  = (const float*)d_in[3];
  const float* bout  = (const float*)d_in[4];
  const float* gamma = (const float*)d_in[5];
  const float* beta  = (const float*)d_in[6];
  char* ws = (char*)d_ws;
  // layout (bytes); att(fp32, 64MB) aliases v+kS which are dead after GEMM1
  u16*   v       = (u16*)(ws + 0);            // 33,554,432
  u16*   kS      = (u16*)(ws + 33554432);     // 33,554,432
  float* att     = (float*)(ws + 0);          // 67,108,864 (alias)
  u16*   qt      = (u16*)(ws + 67108864);     // 33,554,432
  u16*   ctx     = (u16*)(ws + 100663296);    // 33,554,432
  float* partial = (float*)(ws + 134217728);  // 16,777,216
  float* fin     = (float*)(ws + 150994944);  //    524,288
  float* stats   = (float*)(ws + 151519232);  //        512
  float* out = (float*)d_out;

  conv_v  <<<dim3(512), 256, 0, stream>>>(img, wqkv, bqkv, v);
  conv_ksm<<<dim3(512), 256, 0, stream>>>(img, wqkv, bqkv, kS);
  conv_qsm<<<dim3(16, 4, 4), 256, 0, stream>>>(img, wqkv, bqkv, qt);
  // ctx[e][d] = sum_n V[e,n] * K[d,n]
  gemm_bt<u16>  <<<dim3(8, 8, 16), 256, 0, stream>>>(v, kS, ctx);
  // att[e][n] = sum_d ctx[e,d] * qt[n,d]   (att channel = hh*1024 + e)
  gemm_bt<float><<<dim3(8, 8, 16), 256, 0, stream>>>(ctx, qt, att);
  oproj<<<dim3(32, 2, 4), 256, 0, stream>>>(att, wout, partial);
  reduce_stats<<<dim3(16, 4), 256, 0, stream>>>(partial, bout, fin, stats);
  gn_norm<<<dim3(16, 4), 256, 0, stream>>>(fin, stats, gamma, beta, out);
}

// Round 3
// 288.324 us; speedup vs baseline: 1.5446x; 1.5446x over previous
//
#include <hip/hip_runtime.h>
#include <stdint.h>

// Problem constants (B=4, C=32, H=W=32, HEADS=4, DIM_HEAD=32)
#define HID 4096   // hidden = C*HEADS*DIM_HEAD
#define NSP 1024   // H*W
#define CIN 32
// Requires ws_size >= 151,519,744 bytes (~145 MiB)

typedef unsigned short u16;
typedef float f32x4 __attribute__((ext_vector_type(4)));
typedef _Float16 f16;
typedef _Float16 f16x8 __attribute__((ext_vector_type(8)));
typedef unsigned short u16x4 __attribute__((ext_vector_type(4)));
typedef unsigned short u16x8 __attribute__((ext_vector_type(8)));

__device__ __forceinline__ u16 f2h(float f) {
  return __builtin_bit_cast(u16, (f16)f);
}
__device__ __forceinline__ float h2f(u16 u) {
  return (float)__builtin_bit_cast(f16, u);
}

__device__ __forceinline__ void gload16(const u16* g, u16* l) {
  __builtin_amdgcn_global_load_lds(
      (const __attribute__((address_space(1))) void*)g,
      (__attribute__((address_space(3))) void*)l, 16, 0, 0);
}

// ---------------------------------------------------------------------------
// conv_kv: 1x1 conv for one qkv section (K or V). Block = 64 ch x 256 n for
// one b; grid (64, 4, 4). One LDS stage + one barrier. Thread: cg = t>>6
// picks 16 channels, nl = t&63 picks 4 consecutive n. DO_EXP: store
// exp(logit) fp16 UNNORMALIZED (normalization folded into GEMM colscale).
// Output row = (b*4 + (ch&3))*1024 + (ch>>2)   (ch = e*HEADS + hh).
// ---------------------------------------------------------------------------
template <int SECBASE, bool DO_EXP>
__global__ __launch_bounds__(256) void conv_kv(const float* __restrict__ img,
    const float* __restrict__ wq, const float* __restrict__ bq,
    u16* __restrict__ out) {
  __shared__ __align__(16) float imgS[32 * 256];
  __shared__ __align__(16) float wS[32 * 64];
  __shared__ float bS[64];
  int t = threadIdx.x;
  int ch0 = blockIdx.x * 64, nt0 = blockIdx.y * 256, b = blockIdx.z;
  int nl = t & 63, cg = t >> 6;
#pragma unroll
  for (int i = 0; i < 8; i++) {
    int idx = t + i * 256;
    *(f32x4*)&imgS[idx * 4] =
        *(const f32x4*)&img[((size_t)b * CIN + (idx >> 6)) * NSP + nt0 + (idx & 63) * 4];
  }
#pragma unroll
  for (int i = 0; i < 8; i++) {
    int idx = t + i * 256;
    int chl = idx >> 5, c = idx & 31;
    wS[c * 64 + chl] = wq[(size_t)(SECBASE + ch0 + chl) * CIN + c];
  }
  if (t < 64) bS[t] = bq[SECBASE + ch0 + t];
  __syncthreads();
  f32x4 acc[16];
#pragma unroll
  for (int i = 0; i < 16; i++) {
    f32x4 zz = {0.f, 0.f, 0.f, 0.f};
    acc[i] = zz;
  }
#pragma unroll
  for (int c = 0; c < 32; c++) {
    f32x4 x = *(const f32x4*)&imgS[c * 256 + nl * 4];
    const f32x4* wv = (const f32x4*)&wS[c * 64 + cg * 16];
#pragma unroll
    for (int g = 0; g < 4; g++) {
      f32x4 w4 = wv[g];
      acc[g * 4 + 0] += w4[0] * x;
      acc[g * 4 + 1] += w4[1] * x;
      acc[g * 4 + 2] += w4[2] * x;
      acc[g * 4 + 3] += w4[3] * x;
    }
  }
#pragma unroll
  for (int i = 0; i < 16; i++) {
    int ch = ch0 + cg * 16 + i;
    float bias = bS[cg * 16 + i];
    u16x4 o;
#pragma unroll
    for (int j = 0; j < 4; j++) {
      float vv = acc[i][j] + bias;
      if constexpr (DO_EXP) vv = __expf(vv);
      o[j] = f2h(vv);
    }
    size_t row = (size_t)(b * 4 + (ch & 3)) * 1024 + (ch >> 2);
    *(u16x4*)&out[row * NSP + nt0 + nl * 4] = o;
  }
}

// ---------------------------------------------------------------------------
// conv_q: Q section, output TRANSPOSED qt[bh][n][d] = exp(logit) fp16
// UNNORMALIZED. Block = 64 d x 256 n for one bh; grid (16, 4, 16).
// Thread: dl = t&15 picks 4 consecutive d, ng = t>>4 picks 16 n (stride 16).
// Channel for local d: ch = d*HEADS + hh.
// ---------------------------------------------------------------------------
__global__ __launch_bounds__(256) void conv_q(const float* __restrict__ img,
    const float* __restrict__ wq, const float* __restrict__ bq,
    u16* __restrict__ qt) {
  __shared__ __align__(16) float imgS[32 * 256];
  __shared__ __align__(16) float wS[32 * 64];
  __shared__ float bS[64];
  int t = threadIdx.x;
  int d0 = blockIdx.x * 64, nt0 = blockIdx.y * 256, z = blockIdx.z;
  int b = z >> 2, hh = z & 3;
  int dl = t & 15, ng = t >> 4;
#pragma unroll
  for (int i = 0; i < 8; i++) {
    int idx = t + i * 256;
    *(f32x4*)&imgS[idx * 4] =
        *(const f32x4*)&img[((size_t)b * CIN + (idx >> 6)) * NSP + nt0 + (idx & 63) * 4];
  }
#pragma unroll
  for (int i = 0; i < 8; i++) {
    int idx = t + i * 256;
    int chl = idx >> 5, c = idx & 31;
    wS[c * 64 + chl] = wq[(size_t)((d0 + chl) * 4 + hh) * CIN + c];
  }
  if (t < 64) bS[t] = bq[(d0 + t) * 4 + hh];
  __syncthreads();
  f32x4 acc[16];  // acc[j] = 4 d's for n = nt0 + ng + j*16
#pragma unroll
  for (int i = 0; i < 16; i++) {
    f32x4 zz = {0.f, 0.f, 0.f, 0.f};
    acc[i] = zz;
  }
#pragma unroll
  for (int c = 0; c < 32; c++) {
    f32x4 w4 = *(const f32x4*)&wS[c * 64 + dl * 4];
#pragma unroll
    for (int j = 0; j < 16; j++) {
      float x = imgS[c * 256 + ng + j * 16];
      acc[j] += x * w4;
    }
  }
  f32x4 bb = *(const f32x4*)&bS[dl * 4];
  size_t base = (size_t)z * 1024 * 1024;
#pragma unroll
  for (int j = 0; j < 16; j++) {
    int n = nt0 + ng + j * 16;
    u16x4 o;
#pragma unroll
    for (int q = 0; q < 4; q++) o[q] = f2h(__expf(acc[j][q] + bb[q]));
    *(u16x4*)&qt[base + (size_t)n * 1024 + d0 + dl * 4] = o;
  }
}

// ---------------------------------------------------------------------------
// rowinv: per-row inverse sums from the materialized exp buffers (NaN-free
// by construction: sums of positive fp16 > 0). Rows 0..16383 -> kinv from
// kexp; rows 16384..32767 -> qinv (with *scale) from qtexp. One wave per
// row; grid 8192 x 256.
// ---------------------------------------------------------------------------
__global__ __launch_bounds__(256) void rowinv(const u16* __restrict__ kexp,
    const u16* __restrict__ qtexp, float* __restrict__ kinv,
    float* __restrict__ qinv) {
  int t = threadIdx.x;
  int wv = t >> 6, l = t & 63;
  int row = blockIdx.x * 4 + wv;  // 0..32767
  const u16* src = (row < 16384) ? kexp + (size_t)row * 1024
                                 : qtexp + (size_t)(row - 16384) * 1024;
  const u16x8* p = (const u16x8*)(src + l * 16);
  u16x8 a = p[0], bvec = p[1];
  float s = 0.f;
#pragma unroll
  for (int j = 0; j < 8; j++) s += h2f(a[j]) + h2f(bvec[j]);
#pragma unroll
  for (int off = 32; off > 0; off >>= 1) s += __shfl_xor(s, off);
  if (l == 0) {
    s = fmaxf(s, 1e-20f);
    if (row < 16384) kinv[row] = 1.0f / s;
    else qinv[row - 16384] = 0.17677669529663687f / s;  // scale = 32^-0.5
  }
}

// ---------------------------------------------------------------------------
// gemm_bt: batched C = (A * B^T) * colscale[col], M=N=K=1024, 16 batches,
// fp16 in, fp32 accum, fp16 out. 128x128 tile, BK=64, 4 waves of 64x64,
// global_load_lds staging. C/D map: col=lane&15, row=(lane>>4)*4+reg.
// ---------------------------------------------------------------------------
__global__ __launch_bounds__(256) void gemm_bt(const u16* __restrict__ A0,
    const u16* __restrict__ B0, u16* __restrict__ C0,
    const float* __restrict__ colscale) {
  __shared__ __align__(16) u16 As[128 * 64];
  __shared__ __align__(16) u16 Bs[128 * 64];
  int t = threadIdx.x;
  int w = t >> 6, l = t & 63;
  int z = blockIdx.z;
  const u16* A = A0 + (size_t)z * (1024 * 1024) + (size_t)blockIdx.y * 128 * 1024;
  const u16* Bt = B0 + (size_t)z * (1024 * 1024) + (size_t)blockIdx.x * 128 * 1024;
  int wr = w >> 1, wc = w & 1;
  f32x4 acc[4][4];
#pragma unroll
  for (int m = 0; m < 4; m++)
#pragma unroll
    for (int n = 0; n < 4; n++) {
      f32x4 zz = {0.f, 0.f, 0.f, 0.f};
      acc[m][n] = zz;
    }
  int srow = l >> 3, scol = (l & 7) * 8;
  for (int kt = 0; kt < 16; kt++) {
    int k0 = kt * 64;
#pragma unroll
    for (int s = 0; s < 4; s++) {
      int strip = w * 4 + s;
      int r = strip * 8 + srow;
      gload16(A + (size_t)r * 1024 + k0 + scol, &As[strip * 512]);
      gload16(Bt + (size_t)r * 1024 + k0 + scol, &Bs[strip * 512]);
    }
    __syncthreads();
#pragma unroll
    for (int kk = 0; kk < 2; kk++) {
      f16x8 a[4], bb[4];
#pragma unroll
      for (int m = 0; m < 4; m++)
        a[m] = *(const f16x8*)&As[(wr * 64 + m * 16 + (l & 15)) * 64 + kk * 32 + (l >> 4) * 8];
#pragma unroll
      for (int n = 0; n < 4; n++)
        bb[n] = *(const f16x8*)&Bs[(wc * 64 + n * 16 + (l & 15)) * 64 + kk * 32 + (l >> 4) * 8];
#pragma unroll
      for (int m = 0; m < 4; m++)
#pragma unroll
        for (int n = 0; n < 4; n++)
          acc[m][n] = __builtin_amdgcn_mfma_f32_16x16x32_f16(a[m], bb[n], acc[m][n], 0, 0, 0);
    }
    __syncthreads();
  }
  u16* Cp = C0 + (size_t)z * (1024 * 1024);
  const float* csz = colscale + (size_t)z * 1024;
  int rbase = blockIdx.y * 128 + wr * 64 + (l >> 4) * 4;
  int cbase = blockIdx.x * 128 + wc * 64 + (l & 15);
  float sc[4];
#pragma unroll
  for (int n = 0; n < 4; n++) sc[n] = csz[cbase + n * 16];
#pragma unroll
  for (int m = 0; m < 4; m++)
#pragma unroll
    for (int n = 0; n < 4; n++)
#pragma unroll
      for (int j = 0; j < 4; j++) {
        int r = rbase + m * 16 + j;
        int cc = cbase + n * 16;
        Cp[(size_t)r * 1024 + cc] = f2h(acc[m][n][j] * sc[n]);
      }
}

// ---------------------------------------------------------------------------
// oproj: partial[b][kc][o][n] = sum_{c in kc-chunk} att[b][c][n]*w_out[o][c].
// att is fp16. Grid (32 kc, 2 og, 4 b).
// ---------------------------------------------------------------------------
__global__ __launch_bounds__(256) void oproj(const u16* __restrict__ att,
    const float* __restrict__ wout, float* __restrict__ partial) {
  __shared__ __align__(16) float wS[128 * 20];
  int t = threadIdx.x;
  int kc = blockIdx.x, og = blockIdx.y, b = blockIdx.z;
  for (int i = t; i < 128 * 16; i += 256) {
    int cc = i & 127, oo = i >> 7;
    wS[cc * 20 + oo] = wout[(size_t)(og * 16 + oo) * HID + kc * 128 + cc];
  }
  __syncthreads();
  f32x4 acc[16];
#pragma unroll
  for (int o = 0; o < 16; o++) {
    f32x4 zz = {0.f, 0.f, 0.f, 0.f};
    acc[o] = zz;
  }
  const u16* X = att + ((size_t)b * HID + kc * 128) * NSP + t * 4;
#pragma unroll 4
  for (int cc = 0; cc < 128; cc++) {
    u16x4 xr = *(const u16x4*)(X + (size_t)cc * NSP);
    f32x4 x = {h2f(xr[0]), h2f(xr[1]), h2f(xr[2]), h2f(xr[3])};
    const f32x4* wv = (const f32x4*)&wS[cc * 20];
#pragma unroll
    for (int g = 0; g < 4; g++) {
      f32x4 w4 = wv[g];
      acc[g * 4 + 0] += w4[0] * x;
      acc[g * 4 + 1] += w4[1] * x;
      acc[g * 4 + 2] += w4[2] * x;
      acc[g * 4 + 3] += w4[3] * x;
    }
  }
#pragma unroll
  for (int o = 0; o < 16; o++)
    *(f32x4*)&partial[(((size_t)b * 32 + kc) * 32 + og * 16 + o) * NSP + t * 4] = acc[o];
}

// ---------------------------------------------------------------------------
// reduce_stats: sum partials over kc, add bias, write pre-GN fp32 + per-block
// (sum, sumsq) stats.
// ---------------------------------------------------------------------------
__global__ __launch_bounds__(256) void reduce_stats(const float* __restrict__ partial,
    const float* __restrict__ bout, float* __restrict__ fin,
    float* __restrict__ stats) {
  int t = threadIdx.x;
  int nc = blockIdx.x, b = blockIdx.y;
  int nl = t & 63, oq = t >> 6;
  int n = nc * 64 + nl;
  float s1 = 0.f, s2 = 0.f;
#pragma unroll
  for (int oo = 0; oo < 8; oo++) {
    int o = oq * 8 + oo;
    float s = bout[o];
#pragma unroll
    for (int kc = 0; kc < 32; kc++)
      s += partial[(((size_t)b * 32 + kc) * 32 + o) * NSP + n];
    fin[((size_t)b * 32 + o) * NSP + n] = s;
    s1 += s; s2 += s * s;
  }
#pragma unroll
  for (int off = 32; off > 0; off >>= 1) {
    s1 += __shfl_xor(s1, off);
    s2 += __shfl_xor(s2, off);
  }
  __shared__ float r1[4], r2[4];
  int wid = t >> 6;
  if ((t & 63) == 0) { r1[wid] = s1; r2[wid] = s2; }
  __syncthreads();
  if (t == 0) {
    stats[((size_t)b * 16 + nc) * 2 + 0] = r1[0] + r1[1] + r1[2] + r1[3];
    stats[((size_t)b * 16 + nc) * 2 + 1] = r2[0] + r2[1] + r2[2] + r2[3];
  }
}

// ---------------------------------------------------------------------------
// gn_norm: GroupNorm(1, C) per batch.
// ---------------------------------------------------------------------------
__global__ __launch_bounds__(256) void gn_norm(const float* __restrict__ fin,
    const float* __restrict__ stats, const float* __restrict__ gamma,
    const float* __restrict__ beta, float* __restrict__ out) {
  int t = threadIdx.x;
  int nc = blockIdx.x, b = blockIdx.y;
  float s1 = 0.f, s2 = 0.f;
#pragma unroll
  for (int i = 0; i < 16; i++) {
    s1 += stats[((size_t)b * 16 + i) * 2 + 0];
    s2 += stats[((size_t)b * 16 + i) * 2 + 1];
  }
  const float inv_n = 1.0f / 32768.0f;
  float mean = s1 * inv_n;
  float var = s2 * inv_n - mean * mean;
  float rstd = rsqrtf(var + 1e-5f);
  int nl = t & 63, oq = t >> 6;
  int n = nc * 64 + nl;
#pragma unroll
  for (int oo = 0; oo < 8; oo++) {
    int o = oq * 8 + oo;
    float v = fin[((size_t)b * 32 + o) * NSP + n];
    out[((size_t)b * 32 + o) * NSP + n] = (v - mean) * rstd * gamma[o] + beta[o];
  }
}

// ---------------------------------------------------------------------------
extern "C" void kernel_launch(void* const* d_in, const int* in_sizes, int n_in,
                              void* d_out, int out_size, void* d_ws, size_t ws_size,
                              hipStream_t stream) {
  (void)in_sizes; (void)n_in; (void)out_size; (void)ws_size;
  const float* img   = (const float*)d_in[0];
  const float* wqkv  = (const float*)d_in[1];
  const float* bqkv  = (const float*)d_in[2];
  const float* wout  = (const float*)d_in[3];
  const float* bout  = (const float*)d_in[4];
  const float* gamma = (const float*)d_in[5];
  const float* beta  = (const float*)d_in[6];
  char* ws = (char*)d_ws;
  // layout (bytes). att (fp16) aliases v (dead after GEMM1). kinv/qinv live
  // inside the oproj-partial region (consumed by the GEMMs before oproj).
  u16*   v       = (u16*)(ws + 0);            // 33,554,432
  u16*   att     = (u16*)(ws + 0);            // 33,554,432 (alias of v)
  u16*   kexp    = (u16*)(ws + 33554432);     // 33,554,432
  u16*   qtexp   = (u16*)(ws + 67108864);     // 33,554,432
  u16*   ctx     = (u16*)(ws + 100663296);    // 33,554,432
  float* partial = (float*)(ws + 134217728);  // 16,777,216 (oproj)
  float* kinv    = (float*)(ws + 134217728);  //    65,536 (pre-oproj)
  float* qinv    = (float*)(ws + 134283264);  //    65,536 (pre-oproj)
  float* fin     = (float*)(ws + 150994944);  //   524,288
  float* stats   = (float*)(ws + 151519232);  //       512
  float* out = (float*)d_out;

  conv_kv<2 * HID, false><<<dim3(64, 4, 4), 256, 0, stream>>>(img, wqkv, bqkv, v);
  conv_kv<1 * HID, true ><<<dim3(64, 4, 4), 256, 0, stream>>>(img, wqkv, bqkv, kexp);
  conv_q<<<dim3(16, 4, 16), 256, 0, stream>>>(img, wqkv, bqkv, qtexp);
  rowinv<<<dim3(8192), 256, 0, stream>>>(kexp, qtexp, kinv, qinv);
  // ctx[e][d] = (sum_n V[e,n] * Kexp[d,n]) * kinv[d]
  gemm_bt<<<dim3(8, 8, 16), 256, 0, stream>>>(v, kexp, ctx, kinv);
  // att[e][n] = (sum_d ctx[e,d] * qtexp[n,d]) * qinv[n]
  gemm_bt<<<dim3(8, 8, 16), 256, 0, stream>>>(ctx, qtexp, att, qinv);
  oproj<<<dim3(32, 2, 4), 256, 0, stream>>>(att, wout, partial);
  reduce_stats<<<dim3(16, 4), 256, 0, stream>>>(partial, bout, fin, stats);
  gn_norm<<<dim3(16, 4), 256, 0, stream>>>(fin, stats, gamma, beta, out);
}

// Round 4
// 267.854 us; speedup vs baseline: 1.6627x; 1.0764x over previous
//
#include <hip/hip_runtime.h>
#include <stdint.h>

// Problem constants (B=4, C=32, H=W=32, HEADS=4, DIM_HEAD=32)
#define HID 4096   // hidden = C*HEADS*DIM_HEAD
#define NSP 1024   // H*W
#define CIN 32
// Requires ws_size >= 151,519,744 bytes (~145 MiB)

typedef unsigned short u16;
typedef float f32x4 __attribute__((ext_vector_type(4)));
typedef _Float16 f16;
typedef _Float16 f16x8 __attribute__((ext_vector_type(8)));
typedef unsigned short u16x4 __attribute__((ext_vector_type(4)));
typedef unsigned short u16x8 __attribute__((ext_vector_type(8)));

__device__ __forceinline__ u16 f2h(float f) {
  return __builtin_bit_cast(u16, (f16)f);
}
__device__ __forceinline__ float h2f(u16 u) {
  return (float)__builtin_bit_cast(f16, u);
}

__device__ __forceinline__ void gload16(const u16* g, u16* l) {
  __builtin_amdgcn_global_load_lds(
      (const __attribute__((address_space(1))) void*)g,
      (__attribute__((address_space(3))) void*)l, 16, 0, 0);
}

// ---------------------------------------------------------------------------
// conv_kv: 1x1 conv for one qkv section (K or V). Block = 64 ch x 256 n for
// one b; grid (64, 4, 4). One LDS stage + one barrier. Thread: cg = t>>6
// picks 16 channels, nl = t&63 picks 4 consecutive n. DO_EXP: store
// exp(logit) fp16 UNNORMALIZED (normalization folded into GEMM colscale).
// Output row = (b*4 + (ch&3))*1024 + (ch>>2)   (ch = e*HEADS + hh).
// ---------------------------------------------------------------------------
template <int SECBASE, bool DO_EXP>
__global__ __launch_bounds__(256) void conv_kv(const float* __restrict__ img,
    const float* __restrict__ wq, const float* __restrict__ bq,
    u16* __restrict__ out) {
  __shared__ __align__(16) float imgS[32 * 256];
  __shared__ __align__(16) float wS[32 * 64];
  __shared__ float bS[64];
  int t = threadIdx.x;
  int ch0 = blockIdx.x * 64, nt0 = blockIdx.y * 256, b = blockIdx.z;
  int nl = t & 63, cg = t >> 6;
#pragma unroll
  for (int i = 0; i < 8; i++) {
    int idx = t + i * 256;
    *(f32x4*)&imgS[idx * 4] =
        *(const f32x4*)&img[((size_t)b * CIN + (idx >> 6)) * NSP + nt0 + (idx & 63) * 4];
  }
#pragma unroll
  for (int i = 0; i < 8; i++) {
    int idx = t + i * 256;
    int chl = idx >> 5, c = idx & 31;
    wS[c * 64 + chl] = wq[(size_t)(SECBASE + ch0 + chl) * CIN + c];
  }
  if (t < 64) bS[t] = bq[SECBASE + ch0 + t];
  __syncthreads();
  f32x4 acc[16];
#pragma unroll
  for (int i = 0; i < 16; i++) {
    f32x4 zz = {0.f, 0.f, 0.f, 0.f};
    acc[i] = zz;
  }
#pragma unroll
  for (int c = 0; c < 32; c++) {
    f32x4 x = *(const f32x4*)&imgS[c * 256 + nl * 4];
    const f32x4* wv = (const f32x4*)&wS[c * 64 + cg * 16];
#pragma unroll
    for (int g = 0; g < 4; g++) {
      f32x4 w4 = wv[g];
      acc[g * 4 + 0] += w4[0] * x;
      acc[g * 4 + 1] += w4[1] * x;
      acc[g * 4 + 2] += w4[2] * x;
      acc[g * 4 + 3] += w4[3] * x;
    }
  }
#pragma unroll
  for (int i = 0; i < 16; i++) {
    int ch = ch0 + cg * 16 + i;
    float bias = bS[cg * 16 + i];
    u16x4 o;
#pragma unroll
    for (int j = 0; j < 4; j++) {
      float vv = acc[i][j] + bias;
      if constexpr (DO_EXP) vv = __expf(vv);
      o[j] = f2h(vv);
    }
    size_t row = (size_t)(b * 4 + (ch & 3)) * 1024 + (ch >> 2);
    *(u16x4*)&out[row * NSP + nt0 + nl * 4] = o;
  }
}

// ---------------------------------------------------------------------------
// conv_q: Q section, output TRANSPOSED qt[bh][n][d] = exp(logit) fp16
// UNNORMALIZED. Block = 64 d x 256 n for one bh; grid (16, 4, 16).
// Thread: dl = t&15 picks 4 consecutive d, ng = t>>4 picks 16 n (stride 16).
// Channel for local d: ch = d*HEADS + hh.
// ---------------------------------------------------------------------------
__global__ __launch_bounds__(256) void conv_q(const float* __restrict__ img,
    const float* __restrict__ wq, const float* __restrict__ bq,
    u16* __restrict__ qt) {
  __shared__ __align__(16) float imgS[32 * 256];
  __shared__ __align__(16) float wS[32 * 64];
  __shared__ float bS[64];
  int t = threadIdx.x;
  int d0 = blockIdx.x * 64, nt0 = blockIdx.y * 256, z = blockIdx.z;
  int b = z >> 2, hh = z & 3;
  int dl = t & 15, ng = t >> 4;
#pragma unroll
  for (int i = 0; i < 8; i++) {
    int idx = t + i * 256;
    *(f32x4*)&imgS[idx * 4] =
        *(const f32x4*)&img[((size_t)b * CIN + (idx >> 6)) * NSP + nt0 + (idx & 63) * 4];
  }
#pragma unroll
  for (int i = 0; i < 8; i++) {
    int idx = t + i * 256;
    int chl = idx >> 5, c = idx & 31;
    wS[c * 64 + chl] = wq[(size_t)((d0 + chl) * 4 + hh) * CIN + c];
  }
  if (t < 64) bS[t] = bq[(d0 + t) * 4 + hh];
  __syncthreads();
  f32x4 acc[16];  // acc[j] = 4 d's for n = nt0 + ng + j*16
#pragma unroll
  for (int i = 0; i < 16; i++) {
    f32x4 zz = {0.f, 0.f, 0.f, 0.f};
    acc[i] = zz;
  }
#pragma unroll
  for (int c = 0; c < 32; c++) {
    f32x4 w4 = *(const f32x4*)&wS[c * 64 + dl * 4];
#pragma unroll
    for (int j = 0; j < 16; j++) {
      float x = imgS[c * 256 + ng + j * 16];
      acc[j] += x * w4;
    }
  }
  f32x4 bb = *(const f32x4*)&bS[dl * 4];
  size_t base = (size_t)z * 1024 * 1024;
#pragma unroll
  for (int j = 0; j < 16; j++) {
    int n = nt0 + ng + j * 16;
    u16x4 o;
#pragma unroll
    for (int q = 0; q < 4; q++) o[q] = f2h(__expf(acc[j][q] + bb[q]));
    *(u16x4*)&qt[base + (size_t)n * 1024 + d0 + dl * 4] = o;
  }
}

// ---------------------------------------------------------------------------
// rowinv: per-row inverse sums from the materialized exp buffers (NaN-free
// by construction: sums of positive fp16 > 0). Rows 0..16383 -> kinv from
// kexp; rows 16384..32767 -> qinv (with *scale) from qtexp. One wave per
// row; grid 8192 x 256.
// ---------------------------------------------------------------------------
__global__ __launch_bounds__(256) void rowinv(const u16* __restrict__ kexp,
    const u16* __restrict__ qtexp, float* __restrict__ kinv,
    float* __restrict__ qinv) {
  int t = threadIdx.x;
  int wv = t >> 6, l = t & 63;
  int row = blockIdx.x * 4 + wv;  // 0..32767
  const u16* src = (row < 16384) ? kexp + (size_t)row * 1024
                                 : qtexp + (size_t)(row - 16384) * 1024;
  const u16x8* p = (const u16x8*)(src + l * 16);
  u16x8 a = p[0], bvec = p[1];
  float s = 0.f;
#pragma unroll
  for (int j = 0; j < 8; j++) s += h2f(a[j]) + h2f(bvec[j]);
#pragma unroll
  for (int off = 32; off > 0; off >>= 1) s += __shfl_xor(s, off);
  if (l == 0) {
    s = fmaxf(s, 1e-20f);
    if (row < 16384) kinv[row] = 1.0f / s;
    else qinv[row - 16384] = 0.17677669529663687f / s;  // scale = 32^-0.5
  }
}

// ---------------------------------------------------------------------------
// gemm_bt: batched C = (A * B^T) * colscale[col], M=N=K=1024, 16 batches,
// fp16 in, fp32 accum, fp16 out. 128x128 tile, BK=64, 4 waves of 64x64.
// T1: 1D grid 1024, decoded so XCD (= bid&7) == z&7 -> each batch's 4 MB
//     A+B working set stays in one XCD's L2.
// T2: LDS XOR-swizzle, both-sides (rule #21): linear LDS dest for
//     global_load_lds + inverse-swizzled GLOBAL source column + swizzled
//     ds_read address. Post-swizzle: 8 lanes per 16B chunk group = b128
//     conflict floor (conflict-free).
// T3-min: double-buffered LDS; stage(t+1) issued BEFORE compute(t); single
//     __syncthreads() per K-step (its implicit vmcnt(0) drains the stage).
// C/D map: col=lane&15, row=(lane>>4)*4+reg.
// ---------------------------------------------------------------------------
__global__ __launch_bounds__(256) void gemm_bt(const u16* __restrict__ A0,
    const u16* __restrict__ B0, u16* __restrict__ C0,
    const float* __restrict__ colscale) {
  __shared__ __align__(16) u16 As[2][128 * 64];
  __shared__ __align__(16) u16 Bs[2][128 * 64];
  int t = threadIdx.x;
  int w = t >> 6, l = t & 63;
  // T1 decode: bid = (z&7) + 8*((z>>3)*64 + by*8 + bx)
  int bid = blockIdx.x;
  int xcd = bid & 7, rr = bid >> 3;       // rr in [0,128)
  int z = ((rr >> 6) << 3) | xcd;
  int by = (rr >> 3) & 7, bx = rr & 7;
  const u16* A = A0 + (size_t)z * (1024 * 1024) + (size_t)by * 128 * 1024;
  const u16* Bt = B0 + (size_t)z * (1024 * 1024) + (size_t)bx * 128 * 1024;
  int wr = w >> 1, wc = w & 1;
  f32x4 acc[4][4];
#pragma unroll
  for (int m = 0; m < 4; m++)
#pragma unroll
    for (int n = 0; n < 4; n++) {
      f32x4 zz = {0.f, 0.f, 0.f, 0.f};
      acc[m][n] = zz;
    }
  int srow = l >> 3;                        // row-within-strip = (row&7)
  int scol = ((l & 7) ^ srow) * 8;          // T2 inverse-swizzled source col
  auto STAGE = [&](int p, int k0) {
#pragma unroll
    for (int s = 0; s < 4; s++) {
      int strip = w * 4 + s;
      int r = strip * 8 + srow;
      gload16(A + (size_t)r * 1024 + k0 + scol, &As[p][strip * 512]);
      gload16(Bt + (size_t)r * 1024 + k0 + scol, &Bs[p][strip * 512]);
    }
  };
  auto COMPUTE = [&](int p) {
#pragma unroll
    for (int kk = 0; kk < 2; kk++) {
      f16x8 a[4], bb[4];
#pragma unroll
      for (int m = 0; m < 4; m++) {
        int row = wr * 64 + m * 16 + (l & 15);
        int idx = (kk * 32 + (l >> 4) * 8) ^ ((row & 7) * 8);  // T2 read swizzle
        a[m] = *(const f16x8*)&As[p][row * 64 + idx];
      }
#pragma unroll
      for (int n = 0; n < 4; n++) {
        int row = wc * 64 + n * 16 + (l & 15);
        int idx = (kk * 32 + (l >> 4) * 8) ^ ((row & 7) * 8);
        bb[n] = *(const f16x8*)&Bs[p][row * 64 + idx];
      }
#pragma unroll
      for (int m = 0; m < 4; m++)
#pragma unroll
        for (int n = 0; n < 4; n++)
          acc[m][n] = __builtin_amdgcn_mfma_f32_16x16x32_f16(a[m], bb[n], acc[m][n], 0, 0, 0);
    }
  };
  STAGE(0, 0);
  __syncthreads();
  for (int kt = 0; kt < 16; kt += 2) {
    STAGE(1, (kt + 1) * 64);  // kt+1 <= 15 always
    COMPUTE(0);
    __syncthreads();
    if (kt + 2 < 16) STAGE(0, (kt + 2) * 64);
    COMPUTE(1);
    __syncthreads();
  }
  u16* Cp = C0 + (size_t)z * (1024 * 1024);
  const float* csz = colscale + (size_t)z * 1024;
  int rbase = by * 128 + wr * 64 + (l >> 4) * 4;
  int cbase = bx * 128 + wc * 64 + (l & 15);
  float sc[4];
#pragma unroll
  for (int n = 0; n < 4; n++) sc[n] = csz[cbase + n * 16];
#pragma unroll
  for (int m = 0; m < 4; m++)
#pragma unroll
    for (int n = 0; n < 4; n++)
#pragma unroll
      for (int j = 0; j < 4; j++) {
        int r = rbase + m * 16 + j;
        int cc = cbase + n * 16;
        Cp[(size_t)r * 1024 + cc] = f2h(acc[m][n][j] * sc[n]);
      }
}

// ---------------------------------------------------------------------------
// oproj: partial[b][kc][o][n] = sum_{c in kc-chunk} att[b][c][n]*w_out[o][c].
// att is fp16. Grid (32 kc, 2 og, 4 b).
// ---------------------------------------------------------------------------
__global__ __launch_bounds__(256) void oproj(const u16* __restrict__ att,
    const float* __restrict__ wout, float* __restrict__ partial) {
  __shared__ __align__(16) float wS[128 * 20];
  int t = threadIdx.x;
  int kc = blockIdx.x, og = blockIdx.y, b = blockIdx.z;
  for (int i = t; i < 128 * 16; i += 256) {
    int cc = i & 127, oo = i >> 7;
    wS[cc * 20 + oo] = wout[(size_t)(og * 16 + oo) * HID + kc * 128 + cc];
  }
  __syncthreads();
  f32x4 acc[16];
#pragma unroll
  for (int o = 0; o < 16; o++) {
    f32x4 zz = {0.f, 0.f, 0.f, 0.f};
    acc[o] = zz;
  }
  const u16* X = att + ((size_t)b * HID + kc * 128) * NSP + t * 4;
#pragma unroll 4
  for (int cc = 0; cc < 128; cc++) {
    u16x4 xr = *(const u16x4*)(X + (size_t)cc * NSP);
    f32x4 x = {h2f(xr[0]), h2f(xr[1]), h2f(xr[2]), h2f(xr[3])};
    const f32x4* wv = (const f32x4*)&wS[cc * 20];
#pragma unroll
    for (int g = 0; g < 4; g++) {
      f32x4 w4 = wv[g];
      acc[g * 4 + 0] += w4[0] * x;
      acc[g * 4 + 1] += w4[1] * x;
      acc[g * 4 + 2] += w4[2] * x;
      acc[g * 4 + 3] += w4[3] * x;
    }
  }
#pragma unroll
  for (int o = 0; o < 16; o++)
    *(f32x4*)&partial[(((size_t)b * 32 + kc) * 32 + og * 16 + o) * NSP + t * 4] = acc[o];
}

// ---------------------------------------------------------------------------
// reduce_stats: sum partials over kc, add bias, write pre-GN fp32 + per-block
// (sum, sumsq) stats.
// ---------------------------------------------------------------------------
__global__ __launch_bounds__(256) void reduce_stats(const float* __restrict__ partial,
    const float* __restrict__ bout, float* __restrict__ fin,
    float* __restrict__ stats) {
  int t = threadIdx.x;
  int nc = blockIdx.x, b = blockIdx.y;
  int nl = t & 63, oq = t >> 6;
  int n = nc * 64 + nl;
  float s1 = 0.f, s2 = 0.f;
#pragma unroll
  for (int oo = 0; oo < 8; oo++) {
    int o = oq * 8 + oo;
    float s = bout[o];
#pragma unroll
    for (int kc = 0; kc < 32; kc++)
      s += partial[(((size_t)b * 32 + kc) * 32 + o) * NSP + n];
    fin[((size_t)b * 32 + o) * NSP + n] = s;
    s1 += s; s2 += s * s;
  }
#pragma unroll
  for (int off = 32; off > 0; off >>= 1) {
    s1 += __shfl_xor(s1, off);
    s2 += __shfl_xor(s2, off);
  }
  __shared__ float r1[4], r2[4];
  int wid = t >> 6;
  if ((t & 63) == 0) { r1[wid] = s1; r2[wid] = s2; }
  __syncthreads();
  if (t == 0) {
    stats[((size_t)b * 16 + nc) * 2 + 0] = r1[0] + r1[1] + r1[2] + r1[3];
    stats[((size_t)b * 16 + nc) * 2 + 1] = r2[0] + r2[1] + r2[2] + r2[3];
  }
}

// ---------------------------------------------------------------------------
// gn_norm: GroupNorm(1, C) per batch.
// ---------------------------------------------------------------------------
__global__ __launch_bounds__(256) void gn_norm(const float* __restrict__ fin,
    const float* __restrict__ stats, const float* __restrict__ gamma,
    const float* __restrict__ beta, float* __restrict__ out) {
  int t = threadIdx.x;
  int nc = blockIdx.x, b = blockIdx.y;
  float s1 = 0.f, s2 = 0.f;
#pragma unroll
  for (int i = 0; i < 16; i++) {
    s1 += stats[((size_t)b * 16 + i) * 2 + 0];
    s2 += stats[((size_t)b * 16 + i) * 2 + 1];
  }
  const float inv_n = 1.0f / 32768.0f;
  float mean = s1 * inv_n;
  float var = s2 * inv_n - mean * mean;
  float rstd = rsqrtf(var + 1e-5f);
  int nl = t & 63, oq = t >> 6;
  int n = nc * 64 + nl;
#pragma unroll
  for (int oo = 0; oo < 8; oo++) {
    int o = oq * 8 + oo;
    float v = fin[((size_t)b * 32 + o) * NSP + n];
    out[((size_t)b * 32 + o) * NSP + n] = (v - mean) * rstd * gamma[o] + beta[o];
  }
}

// ---------------------------------------------------------------------------
extern "C" void kernel_launch(void* const* d_in, const int* in_sizes, int n_in,
                              void* d_out, int out_size, void* d_ws, size_t ws_size,
                              hipStream_t stream) {
  (void)in_sizes; (void)n_in; (void)out_size; (void)ws_size;
  const float* img   = (const float*)d_in[0];
  const float* wqkv  = (const float*)d_in[1];
  const float* bqkv  = (const float*)d_in[2];
  const float* wout  = (const float*)d_in[3];
  const float* bout  = (const float*)d_in[4];
  const float* gamma = (const float*)d_in[5];
  const float* beta  = (const float*)d_in[6];
  char* ws = (char*)d_ws;
  // layout (bytes). att (fp16) aliases v (dead after GEMM1). kinv/qinv live
  // inside the oproj-partial region (consumed by the GEMMs before oproj).
  u16*   v       = (u16*)(ws + 0);            // 33,554,432
  u16*   att     = (u16*)(ws + 0);            // 33,554,432 (alias of v)
  u16*   kexp    = (u16*)(ws + 33554432);     // 33,554,432
  u16*   qtexp   = (u16*)(ws + 67108864);     // 33,554,432
  u16*   ctx     = (u16*)(ws + 100663296);    // 33,554,432
  float* partial = (float*)(ws + 134217728);  // 16,777,216 (oproj)
  float* kinv    = (float*)(ws + 134217728);  //    65,536 (pre-oproj)
  float* qinv    = (float*)(ws + 134283264);  //    65,536 (pre-oproj)
  float* fin     = (float*)(ws + 150994944);  //   524,288
  float* stats   = (float*)(ws + 151519232);  //       512
  float* out = (float*)d_out;

  conv_kv<2 * HID, false><<<dim3(64, 4, 4), 256, 0, stream>>>(img, wqkv, bqkv, v);
  conv_kv<1 * HID, true ><<<dim3(64, 4, 4), 256, 0, stream>>>(img, wqkv, bqkv, kexp);
  conv_q<<<dim3(16, 4, 16), 256, 0, stream>>>(img, wqkv, bqkv, qtexp);
  rowinv<<<dim3(8192), 256, 0, stream>>>(kexp, qtexp, kinv, qinv);
  // ctx[e][d] = (sum_n V[e,n] * Kexp[d,n]) * kinv[d]
  gemm_bt<<<dim3(1024), 256, 0, stream>>>(v, kexp, ctx, kinv);
  // att[e][n] = (sum_d ctx[e,d] * qtexp[n,d]) * qinv[n]
  gemm_bt<<<dim3(1024), 256, 0, stream>>>(ctx, qtexp, att, qinv);
  oproj<<<dim3(32, 2, 4), 256, 0, stream>>>(att, wout, partial);
  reduce_stats<<<dim3(16, 4), 256, 0, stream>>>(partial, bout, fin, stats);
  gn_norm<<<dim3(16, 4), 256, 0, stream>>>(fin, stats, gamma, beta, out);
}

// Round 5
// 214.327 us; speedup vs baseline: 2.0779x; 1.2497x over previous
//
#include <hip/hip_runtime.h>
#include <stdint.h>

// Problem constants (B=4, C=32, H=W=32, HEADS=4, DIM_HEAD=32)
#define HID 4096   // hidden = C*HEADS*DIM_HEAD
#define NSP 1024   // H*W
#define CIN 32
// Requires ws_size >= 151,519,744 bytes (~145 MiB)

typedef unsigned short u16;
typedef float f32x4 __attribute__((ext_vector_type(4)));
typedef _Float16 f16;
typedef _Float16 f16x8 __attribute__((ext_vector_type(8)));
typedef unsigned short u16x4 __attribute__((ext_vector_type(4)));
typedef unsigned short u16x8 __attribute__((ext_vector_type(8)));

__device__ __forceinline__ u16 f2h(float f) {
  return __builtin_bit_cast(u16, (f16)f);
}
__device__ __forceinline__ float h2f(u16 u) {
  return (float)__builtin_bit_cast(f16, u);
}

__device__ __forceinline__ void gload16(const u16* g, u16* l) {
  __builtin_amdgcn_global_load_lds(
      (const __attribute__((address_space(1))) void*)g,
      (__attribute__((address_space(3))) void*)l, 16, 0, 0);
}

// ---------------------------------------------------------------------------
// conv_kv: 1x1 conv for one qkv section (K or V). Block = 64 ch x 256 n for
// one b; grid (64, 4, 4). One LDS stage + one barrier. Thread: cg = t>>6
// picks 16 channels, nl = t&63 picks 4 consecutive n. DO_EXP: store
// exp(logit) fp16 UNNORMALIZED (normalization folded into GEMM colscale).
// Output row = (b*4 + (ch&3))*1024 + (ch>>2)   (ch = e*HEADS + hh).
// ---------------------------------------------------------------------------
template <int SECBASE, bool DO_EXP>
__global__ __launch_bounds__(256) void conv_kv(const float* __restrict__ img,
    const float* __restrict__ wq, const float* __restrict__ bq,
    u16* __restrict__ out) {
  __shared__ __align__(16) float imgS[32 * 256];
  __shared__ __align__(16) float wS[32 * 64];
  __shared__ float bS[64];
  int t = threadIdx.x;
  int ch0 = blockIdx.x * 64, nt0 = blockIdx.y * 256, b = blockIdx.z;
  int nl = t & 63, cg = t >> 6;
#pragma unroll
  for (int i = 0; i < 8; i++) {
    int idx = t + i * 256;
    *(f32x4*)&imgS[idx * 4] =
        *(const f32x4*)&img[((size_t)b * CIN + (idx >> 6)) * NSP + nt0 + (idx & 63) * 4];
  }
#pragma unroll
  for (int i = 0; i < 8; i++) {
    int idx = t + i * 256;
    int chl = idx >> 5, c = idx & 31;
    wS[c * 64 + chl] = wq[(size_t)(SECBASE + ch0 + chl) * CIN + c];
  }
  if (t < 64) bS[t] = bq[SECBASE + ch0 + t];
  __syncthreads();
  f32x4 acc[16];
#pragma unroll
  for (int i = 0; i < 16; i++) {
    f32x4 zz = {0.f, 0.f, 0.f, 0.f};
    acc[i] = zz;
  }
#pragma unroll
  for (int c = 0; c < 32; c++) {
    f32x4 x = *(const f32x4*)&imgS[c * 256 + nl * 4];
    const f32x4* wv = (const f32x4*)&wS[c * 64 + cg * 16];
#pragma unroll
    for (int g = 0; g < 4; g++) {
      f32x4 w4 = wv[g];
      acc[g * 4 + 0] += w4[0] * x;
      acc[g * 4 + 1] += w4[1] * x;
      acc[g * 4 + 2] += w4[2] * x;
      acc[g * 4 + 3] += w4[3] * x;
    }
  }
#pragma unroll
  for (int i = 0; i < 16; i++) {
    int ch = ch0 + cg * 16 + i;
    float bias = bS[cg * 16 + i];
    u16x4 o;
#pragma unroll
    for (int j = 0; j < 4; j++) {
      float vv = acc[i][j] + bias;
      if constexpr (DO_EXP) vv = __expf(vv);
      o[j] = f2h(vv);
    }
    size_t row = (size_t)(b * 4 + (ch & 3)) * 1024 + (ch >> 2);
    *(u16x4*)&out[row * NSP + nt0 + nl * 4] = o;
  }
}

// ---------------------------------------------------------------------------
// conv_q: Q section, output TRANSPOSED qt[bh][n][d] = exp(logit) fp16
// UNNORMALIZED. Block = 64 d x 256 n for one bh; grid (16, 4, 16).
// Thread: dl = t&15 picks 4 consecutive d, ng = t>>4 picks 16 n (stride 16).
// Channel for local d: ch = d*HEADS + hh.
// ---------------------------------------------------------------------------
__global__ __launch_bounds__(256) void conv_q(const float* __restrict__ img,
    const float* __restrict__ wq, const float* __restrict__ bq,
    u16* __restrict__ qt) {
  __shared__ __align__(16) float imgS[32 * 256];
  __shared__ __align__(16) float wS[32 * 64];
  __shared__ float bS[64];
  int t = threadIdx.x;
  int d0 = blockIdx.x * 64, nt0 = blockIdx.y * 256, z = blockIdx.z;
  int b = z >> 2, hh = z & 3;
  int dl = t & 15, ng = t >> 4;
#pragma unroll
  for (int i = 0; i < 8; i++) {
    int idx = t + i * 256;
    *(f32x4*)&imgS[idx * 4] =
        *(const f32x4*)&img[((size_t)b * CIN + (idx >> 6)) * NSP + nt0 + (idx & 63) * 4];
  }
#pragma unroll
  for (int i = 0; i < 8; i++) {
    int idx = t + i * 256;
    int chl = idx >> 5, c = idx & 31;
    wS[c * 64 + chl] = wq[(size_t)((d0 + chl) * 4 + hh) * CIN + c];
  }
  if (t < 64) bS[t] = bq[(d0 + t) * 4 + hh];
  __syncthreads();
  f32x4 acc[16];  // acc[j] = 4 d's for n = nt0 + ng + j*16
#pragma unroll
  for (int i = 0; i < 16; i++) {
    f32x4 zz = {0.f, 0.f, 0.f, 0.f};
    acc[i] = zz;
  }
#pragma unroll
  for (int c = 0; c < 32; c++) {
    f32x4 w4 = *(const f32x4*)&wS[c * 64 + dl * 4];
#pragma unroll
    for (int j = 0; j < 16; j++) {
      float x = imgS[c * 256 + ng + j * 16];
      acc[j] += x * w4;
    }
  }
  f32x4 bb = *(const f32x4*)&bS[dl * 4];
  size_t base = (size_t)z * 1024 * 1024;
#pragma unroll
  for (int j = 0; j < 16; j++) {
    int n = nt0 + ng + j * 16;
    u16x4 o;
#pragma unroll
    for (int q = 0; q < 4; q++) o[q] = f2h(__expf(acc[j][q] + bb[q]));
    *(u16x4*)&qt[base + (size_t)n * 1024 + d0 + dl * 4] = o;
  }
}

// ---------------------------------------------------------------------------
// rowinv: per-row inverse sums from the materialized exp buffers (NaN-free
// by construction: sums of positive fp16 > 0). Rows 0..16383 -> kinv from
// kexp; rows 16384..32767 -> qinv (with *scale) from qtexp. One wave per
// row; grid 8192 x 256.
// ---------------------------------------------------------------------------
__global__ __launch_bounds__(256) void rowinv(const u16* __restrict__ kexp,
    const u16* __restrict__ qtexp, float* __restrict__ kinv,
    float* __restrict__ qinv) {
  int t = threadIdx.x;
  int wv = t >> 6, l = t & 63;
  int row = blockIdx.x * 4 + wv;  // 0..32767
  const u16* src = (row < 16384) ? kexp + (size_t)row * 1024
                                 : qtexp + (size_t)(row - 16384) * 1024;
  const u16x8* p = (const u16x8*)(src + l * 16);
  u16x8 a = p[0], bvec = p[1];
  float s = 0.f;
#pragma unroll
  for (int j = 0; j < 8; j++) s += h2f(a[j]) + h2f(bvec[j]);
#pragma unroll
  for (int off = 32; off > 0; off >>= 1) s += __shfl_xor(s, off);
  if (l == 0) {
    s = fmaxf(s, 1e-20f);
    if (row < 16384) kinv[row] = 1.0f / s;
    else qinv[row - 16384] = 0.17677669529663687f / s;  // scale = 32^-0.5
  }
}

// ---------------------------------------------------------------------------
// gemm_bt: batched C = (A * B^T) * colscale[col], M=N=K=1024, 16 batches,
// fp16 in, fp32 accum, fp16 out. 128x128 tile, BK=64, 4 waves of 64x64.
// T1: 1D grid 1024, decoded so XCD (= bid&7) == z&7 -> each batch's 4 MB
//     A+B working set stays in one XCD's L2.
// T2: LDS XOR-swizzle, both-sides (rule #21): linear LDS dest for
//     global_load_lds + inverse-swizzled GLOBAL source column + swizzled
//     ds_read address.
// T3-min: double-buffered LDS; stage(t+1) issued BEFORE compute(t); single
//     __syncthreads() per K-step (its implicit vmcnt(0) drains the stage).
// C/D map: col=lane&15, row=(lane>>4)*4+reg.
// ---------------------------------------------------------------------------
__global__ __launch_bounds__(256) void gemm_bt(const u16* __restrict__ A0,
    const u16* __restrict__ B0, u16* __restrict__ C0,
    const float* __restrict__ colscale) {
  __shared__ __align__(16) u16 As[2][128 * 64];
  __shared__ __align__(16) u16 Bs[2][128 * 64];
  int t = threadIdx.x;
  int w = t >> 6, l = t & 63;
  // T1 decode: bid = (z&7) + 8*((z>>3)*64 + by*8 + bx)
  int bid = blockIdx.x;
  int xcd = bid & 7, rr = bid >> 3;       // rr in [0,128)
  int z = ((rr >> 6) << 3) | xcd;
  int by = (rr >> 3) & 7, bx = rr & 7;
  const u16* A = A0 + (size_t)z * (1024 * 1024) + (size_t)by * 128 * 1024;
  const u16* Bt = B0 + (size_t)z * (1024 * 1024) + (size_t)bx * 128 * 1024;
  int wr = w >> 1, wc = w & 1;
  f32x4 acc[4][4];
#pragma unroll
  for (int m = 0; m < 4; m++)
#pragma unroll
    for (int n = 0; n < 4; n++) {
      f32x4 zz = {0.f, 0.f, 0.f, 0.f};
      acc[m][n] = zz;
    }
  int srow = l >> 3;                        // row-within-strip = (row&7)
  int scol = ((l & 7) ^ srow) * 8;          // T2 inverse-swizzled source col
  auto STAGE = [&](int p, int k0) {
#pragma unroll
    for (int s = 0; s < 4; s++) {
      int strip = w * 4 + s;
      int r = strip * 8 + srow;
      gload16(A + (size_t)r * 1024 + k0 + scol, &As[p][strip * 512]);
      gload16(Bt + (size_t)r * 1024 + k0 + scol, &Bs[p][strip * 512]);
    }
  };
  auto COMPUTE = [&](int p) {
#pragma unroll
    for (int kk = 0; kk < 2; kk++) {
      f16x8 a[4], bb[4];
#pragma unroll
      for (int m = 0; m < 4; m++) {
        int row = wr * 64 + m * 16 + (l & 15);
        int idx = (kk * 32 + (l >> 4) * 8) ^ ((row & 7) * 8);  // T2 read swizzle
        a[m] = *(const f16x8*)&As[p][row * 64 + idx];
      }
#pragma unroll
      for (int n = 0; n < 4; n++) {
        int row = wc * 64 + n * 16 + (l & 15);
        int idx = (kk * 32 + (l >> 4) * 8) ^ ((row & 7) * 8);
        bb[n] = *(const f16x8*)&Bs[p][row * 64 + idx];
      }
#pragma unroll
      for (int m = 0; m < 4; m++)
#pragma unroll
        for (int n = 0; n < 4; n++)
          acc[m][n] = __builtin_amdgcn_mfma_f32_16x16x32_f16(a[m], bb[n], acc[m][n], 0, 0, 0);
    }
  };
  STAGE(0, 0);
  __syncthreads();
  for (int kt = 0; kt < 16; kt += 2) {
    STAGE(1, (kt + 1) * 64);  // kt+1 <= 15 always
    COMPUTE(0);
    __syncthreads();
    if (kt + 2 < 16) STAGE(0, (kt + 2) * 64);
    COMPUTE(1);
    __syncthreads();
  }
  u16* Cp = C0 + (size_t)z * (1024 * 1024);
  const float* csz = colscale + (size_t)z * 1024;
  int rbase = by * 128 + wr * 64 + (l >> 4) * 4;
  int cbase = bx * 128 + wc * 64 + (l & 15);
  float sc[4];
#pragma unroll
  for (int n = 0; n < 4; n++) sc[n] = csz[cbase + n * 16];
#pragma unroll
  for (int m = 0; m < 4; m++)
#pragma unroll
    for (int n = 0; n < 4; n++)
#pragma unroll
      for (int j = 0; j < 4; j++) {
        int r = rbase + m * 16 + j;
        int cc = cbase + n * 16;
        Cp[(size_t)r * 1024 + cc] = f2h(acc[m][n][j] * sc[n]);
      }
}

// ---------------------------------------------------------------------------
// oproj: partial[b][kc][o][n] = sum_{c in kc-chunk} att[b][c][n]*w_out[o][c].
// att is fp16. Grid (32 kc, 2 og, 4 b).
// ---------------------------------------------------------------------------
__global__ __launch_bounds__(256) void oproj(const u16* __restrict__ att,
    const float* __restrict__ wout, float* __restrict__ partial) {
  __shared__ __align__(16) float wS[128 * 20];
  int t = threadIdx.x;
  int kc = blockIdx.x, og = blockIdx.y, b = blockIdx.z;
  for (int i = t; i < 128 * 16; i += 256) {
    int cc = i & 127, oo = i >> 7;
    wS[cc * 20 + oo] = wout[(size_t)(og * 16 + oo) * HID + kc * 128 + cc];
  }
  __syncthreads();
  f32x4 acc[16];
#pragma unroll
  for (int o = 0; o < 16; o++) {
    f32x4 zz = {0.f, 0.f, 0.f, 0.f};
    acc[o] = zz;
  }
  const u16* X = att + ((size_t)b * HID + kc * 128) * NSP + t * 4;
#pragma unroll 4
  for (int cc = 0; cc < 128; cc++) {
    u16x4 xr = *(const u16x4*)(X + (size_t)cc * NSP);
    f32x4 x = {h2f(xr[0]), h2f(xr[1]), h2f(xr[2]), h2f(xr[3])};
    const f32x4* wv = (const f32x4*)&wS[cc * 20];
#pragma unroll
    for (int g = 0; g < 4; g++) {
      f32x4 w4 = wv[g];
      acc[g * 4 + 0] += w4[0] * x;
      acc[g * 4 + 1] += w4[1] * x;
      acc[g * 4 + 2] += w4[2] * x;
      acc[g * 4 + 3] += w4[3] * x;
    }
  }
#pragma unroll
  for (int o = 0; o < 16; o++)
    *(f32x4*)&partial[(((size_t)b * 32 + kc) * 32 + og * 16 + o) * NSP + t * 4] = acc[o];
}

// ---------------------------------------------------------------------------
// reduce_stats: one thread per output element (b,o,n); 32 kc-partials loaded
// into INDEPENDENT registers (32 loads in flight), tree-summed. Grid 512
// blocks x 256 thr. Per-block (sum,sumsq) -> stats[blockIdx][2]; blocks
// 128*b .. 128*b+127 belong to batch b (gn_norm aggregates).
// ---------------------------------------------------------------------------
__global__ __launch_bounds__(256) void reduce_stats(const float* __restrict__ partial,
    const float* __restrict__ bout, float* __restrict__ fin,
    float* __restrict__ stats) {
  int t = threadIdx.x;
  int gid = blockIdx.x * 256 + t;  // 131072 = 4b * 32o * 1024n
  int n = gid & 1023;
  int o = (gid >> 10) & 31;
  int b = gid >> 15;
  const float* p = partial + ((size_t)b * 32 * 32 + o) * NSP + n;
  float v[32];
#pragma unroll
  for (int kc = 0; kc < 32; kc++) v[kc] = p[(size_t)kc * 32 * NSP];
  float s = bout[o];
#pragma unroll
  for (int kc = 0; kc < 32; kc++) s += v[kc];
  fin[((size_t)b * 32 + o) * NSP + n] = s;
  float s1 = s, s2 = s * s;
#pragma unroll
  for (int off = 32; off > 0; off >>= 1) {
    s1 += __shfl_xor(s1, off);
    s2 += __shfl_xor(s2, off);
  }
  __shared__ float r1[4], r2[4];
  int wid = t >> 6;
  if ((t & 63) == 0) { r1[wid] = s1; r2[wid] = s2; }
  __syncthreads();
  if (t == 0) {
    stats[blockIdx.x * 2 + 0] = r1[0] + r1[1] + r1[2] + r1[3];
    stats[blockIdx.x * 2 + 1] = r2[0] + r2[1] + r2[2] + r2[3];
  }
}

// ---------------------------------------------------------------------------
// gn_norm: GroupNorm(1, C) per batch; aggregates 128 per-block stats.
// ---------------------------------------------------------------------------
__global__ __launch_bounds__(256) void gn_norm(const float* __restrict__ fin,
    const float* __restrict__ stats, const float* __restrict__ gamma,
    const float* __restrict__ beta, float* __restrict__ out) {
  int t = threadIdx.x;
  int nc = blockIdx.x, b = blockIdx.y;
  float s1 = 0.f, s2 = 0.f;
  for (int i = 0; i < 128; i++) {  // uniform broadcast loads (L2-hit)
    s1 += stats[(b * 128 + i) * 2 + 0];
    s2 += stats[(b * 128 + i) * 2 + 1];
  }
  const float inv_n = 1.0f / 32768.0f;
  float mean = s1 * inv_n;
  float var = s2 * inv_n - mean * mean;
  float rstd = rsqrtf(var + 1e-5f);
  int nl = t & 63, oq = t >> 6;
  int n = nc * 64 + nl;
#pragma unroll
  for (int oo = 0; oo < 8; oo++) {
    int o = oq * 8 + oo;
    float v = fin[((size_t)b * 32 + o) * NSP + n];
    out[((size_t)b * 32 + o) * NSP + n] = (v - mean) * rstd * gamma[o] + beta[o];
  }
}

// ---------------------------------------------------------------------------
extern "C" void kernel_launch(void* const* d_in, const int* in_sizes, int n_in,
                              void* d_out, int out_size, void* d_ws, size_t ws_size,
                              hipStream_t stream) {
  (void)in_sizes; (void)n_in; (void)out_size; (void)ws_size;
  const float* img   = (const float*)d_in[0];
  const float* wqkv  = (const float*)d_in[1];
  const float* bqkv  = (const float*)d_in[2];
  const float* wout  = (const float*)d_in[3];
  const float* bout  = (const float*)d_in[4];
  const float* gamma = (const float*)d_in[5];
  const float* beta  = (const float*)d_in[6];
  char* ws = (char*)d_ws;
  // layout (bytes). att (fp16) aliases v (dead after GEMM1). kinv/qinv live
  // inside the oproj-partial region (consumed by the GEMMs before oproj).
  // stats lives in the ctx region (dead after GEMM2).
  u16*   v       = (u16*)(ws + 0);            // 33,554,432
  u16*   att     = (u16*)(ws + 0);            // 33,554,432 (alias of v)
  u16*   kexp    = (u16*)(ws + 33554432);     // 33,554,432
  u16*   qtexp   = (u16*)(ws + 67108864);     // 33,554,432
  u16*   ctx     = (u16*)(ws + 100663296);    // 33,554,432
  float* stats   = (float*)(ws + 100663296);  //     4,096 (alias of ctx)
  float* partial = (float*)(ws + 134217728);  // 16,777,216 (oproj)
  float* kinv    = (float*)(ws + 134217728);  //    65,536 (pre-oproj)
  float* qinv    = (float*)(ws + 134283264);  //    65,536 (pre-oproj)
  float* fin     = (float*)(ws + 150994944);  //   524,288
  float* out = (float*)d_out;

  conv_kv<2 * HID, false><<<dim3(64, 4, 4), 256, 0, stream>>>(img, wqkv, bqkv, v);
  conv_kv<1 * HID, true ><<<dim3(64, 4, 4), 256, 0, stream>>>(img, wqkv, bqkv, kexp);
  conv_q<<<dim3(16, 4, 16), 256, 0, stream>>>(img, wqkv, bqkv, qtexp);
  rowinv<<<dim3(8192), 256, 0, stream>>>(kexp, qtexp, kinv, qinv);
  // ctx[e][d] = (sum_n V[e,n] * Kexp[d,n]) * kinv[d]
  gemm_bt<<<dim3(1024), 256, 0, stream>>>(v, kexp, ctx, kinv);
  // att[e][n] = (sum_d ctx[e,d] * qtexp[n,d]) * qinv[n]
  gemm_bt<<<dim3(1024), 256, 0, stream>>>(ctx, qtexp, att, qinv);
  oproj<<<dim3(32, 2, 4), 256, 0, stream>>>(att, wout, partial);
  reduce_stats<<<dim3(512), 256, 0, stream>>>(partial, bout, fin, stats);
  gn_norm<<<dim3(16, 4), 256, 0, stream>>>(fin, stats, gamma, beta, out);
}

// Round 6
// 206.031 us; speedup vs baseline: 2.1616x; 1.0403x over previous
//
#include <hip/hip_runtime.h>
#include <stdint.h>

// Problem constants (B=4, C=32, H=W=32, HEADS=4, DIM_HEAD=32)
#define HID 4096   // hidden = C*HEADS*DIM_HEAD
#define NSP 1024   // H*W
#define CIN 32
// Requires ws_size >= 151,519,744 bytes (~145 MiB)

typedef unsigned short u16;
typedef float f32x4 __attribute__((ext_vector_type(4)));
typedef _Float16 f16;
typedef _Float16 f16x8 __attribute__((ext_vector_type(8)));
typedef unsigned short u16x4 __attribute__((ext_vector_type(4)));
typedef unsigned short u16x8 __attribute__((ext_vector_type(8)));

__device__ __forceinline__ u16 f2h(float f) {
  return __builtin_bit_cast(u16, (f16)f);
}
__device__ __forceinline__ float h2f(u16 u) {
  return (float)__builtin_bit_cast(f16, u);
}

__device__ __forceinline__ void gload16(const u16* g, u16* l) {
  __builtin_amdgcn_global_load_lds(
      (const __attribute__((address_space(1))) void*)g,
      (__attribute__((address_space(3))) void*)l, 16, 0, 0);
}

// ---------------------------------------------------------------------------
// conv_kv: 1x1 conv for one qkv section (K or V). Block = 64 ch x 256 n for
// one b; grid (64, 4, 4). DO_EXP: store exp(logit) fp16 UNNORMALIZED.
// Output row = (b*4 + (ch&3))*1024 + (ch>>2)   (ch = e*HEADS + hh).
// ---------------------------------------------------------------------------
template <int SECBASE, bool DO_EXP>
__global__ __launch_bounds__(256) void conv_kv(const float* __restrict__ img,
    const float* __restrict__ wq, const float* __restrict__ bq,
    u16* __restrict__ out) {
  __shared__ __align__(16) float imgS[32 * 256];
  __shared__ __align__(16) float wS[32 * 64];
  __shared__ float bS[64];
  int t = threadIdx.x;
  int ch0 = blockIdx.x * 64, nt0 = blockIdx.y * 256, b = blockIdx.z;
  int nl = t & 63, cg = t >> 6;
#pragma unroll
  for (int i = 0; i < 8; i++) {
    int idx = t + i * 256;
    *(f32x4*)&imgS[idx * 4] =
        *(const f32x4*)&img[((size_t)b * CIN + (idx >> 6)) * NSP + nt0 + (idx & 63) * 4];
  }
#pragma unroll
  for (int i = 0; i < 8; i++) {
    int idx = t + i * 256;
    int chl = idx >> 5, c = idx & 31;
    wS[c * 64 + chl] = wq[(size_t)(SECBASE + ch0 + chl) * CIN + c];
  }
  if (t < 64) bS[t] = bq[SECBASE + ch0 + t];
  __syncthreads();
  f32x4 acc[16];
#pragma unroll
  for (int i = 0; i < 16; i++) {
    f32x4 zz = {0.f, 0.f, 0.f, 0.f};
    acc[i] = zz;
  }
#pragma unroll
  for (int c = 0; c < 32; c++) {
    f32x4 x = *(const f32x4*)&imgS[c * 256 + nl * 4];
    const f32x4* wv = (const f32x4*)&wS[c * 64 + cg * 16];
#pragma unroll
    for (int g = 0; g < 4; g++) {
      f32x4 w4 = wv[g];
      acc[g * 4 + 0] += w4[0] * x;
      acc[g * 4 + 1] += w4[1] * x;
      acc[g * 4 + 2] += w4[2] * x;
      acc[g * 4 + 3] += w4[3] * x;
    }
  }
#pragma unroll
  for (int i = 0; i < 16; i++) {
    int ch = ch0 + cg * 16 + i;
    float bias = bS[cg * 16 + i];
    u16x4 o;
#pragma unroll
    for (int j = 0; j < 4; j++) {
      float vv = acc[i][j] + bias;
      if constexpr (DO_EXP) vv = __expf(vv);
      o[j] = f2h(vv);
    }
    size_t row = (size_t)(b * 4 + (ch & 3)) * 1024 + (ch >> 2);
    *(u16x4*)&out[row * NSP + nt0 + nl * 4] = o;
  }
}

// ---------------------------------------------------------------------------
// conv_q: Q section, output TRANSPOSED qt[bh][n][d] = exp(logit) fp16
// UNNORMALIZED. Block = 64 d x 256 n for one bh; grid (16, 4, 16).
// ---------------------------------------------------------------------------
__global__ __launch_bounds__(256) void conv_q(const float* __restrict__ img,
    const float* __restrict__ wq, const float* __restrict__ bq,
    u16* __restrict__ qt) {
  __shared__ __align__(16) float imgS[32 * 256];
  __shared__ __align__(16) float wS[32 * 64];
  __shared__ float bS[64];
  int t = threadIdx.x;
  int d0 = blockIdx.x * 64, nt0 = blockIdx.y * 256, z = blockIdx.z;
  int b = z >> 2, hh = z & 3;
  int dl = t & 15, ng = t >> 4;
#pragma unroll
  for (int i = 0; i < 8; i++) {
    int idx = t + i * 256;
    *(f32x4*)&imgS[idx * 4] =
        *(const f32x4*)&img[((size_t)b * CIN + (idx >> 6)) * NSP + nt0 + (idx & 63) * 4];
  }
#pragma unroll
  for (int i = 0; i < 8; i++) {
    int idx = t + i * 256;
    int chl = idx >> 5, c = idx & 31;
    wS[c * 64 + chl] = wq[(size_t)((d0 + chl) * 4 + hh) * CIN + c];
  }
  if (t < 64) bS[t] = bq[(d0 + t) * 4 + hh];
  __syncthreads();
  f32x4 acc[16];  // acc[j] = 4 d's for n = nt0 + ng + j*16
#pragma unroll
  for (int i = 0; i < 16; i++) {
    f32x4 zz = {0.f, 0.f, 0.f, 0.f};
    acc[i] = zz;
  }
#pragma unroll
  for (int c = 0; c < 32; c++) {
    f32x4 w4 = *(const f32x4*)&wS[c * 64 + dl * 4];
#pragma unroll
    for (int j = 0; j < 16; j++) {
      float x = imgS[c * 256 + ng + j * 16];
      acc[j] += x * w4;
    }
  }
  f32x4 bb = *(const f32x4*)&bS[dl * 4];
  size_t base = (size_t)z * 1024 * 1024;
#pragma unroll
  for (int j = 0; j < 16; j++) {
    int n = nt0 + ng + j * 16;
    u16x4 o;
#pragma unroll
    for (int q = 0; q < 4; q++) o[q] = f2h(__expf(acc[j][q] + bb[q]));
    *(u16x4*)&qt[base + (size_t)n * 1024 + d0 + dl * 4] = o;
  }
}

// ---------------------------------------------------------------------------
// rowinv: per-row inverse sums from the materialized exp buffers.
// ---------------------------------------------------------------------------
__global__ __launch_bounds__(256) void rowinv(const u16* __restrict__ kexp,
    const u16* __restrict__ qtexp, float* __restrict__ kinv,
    float* __restrict__ qinv) {
  int t = threadIdx.x;
  int wv = t >> 6, l = t & 63;
  int row = blockIdx.x * 4 + wv;  // 0..32767
  const u16* src = (row < 16384) ? kexp + (size_t)row * 1024
                                 : qtexp + (size_t)(row - 16384) * 1024;
  const u16x8* p = (const u16x8*)(src + l * 16);
  u16x8 a = p[0], bvec = p[1];
  float s = 0.f;
#pragma unroll
  for (int j = 0; j < 8; j++) s += h2f(a[j]) + h2f(bvec[j]);
#pragma unroll
  for (int off = 32; off > 0; off >>= 1) s += __shfl_xor(s, off);
  if (l == 0) {
    s = fmaxf(s, 1e-20f);
    if (row < 16384) kinv[row] = 1.0f / s;
    else qinv[row - 16384] = 0.17677669529663687f / s;  // scale = 32^-0.5
  }
}

// ---------------------------------------------------------------------------
// gemm8: batched C = (A * B^T) * colscale[col], M=N=K=1024, 16 batches.
// 256x256 tile, BK=64, 8 waves (2M x 4N), 512 thr, LDS 128 KB (2 dbuf).
// Phase-pipelined schedule (T3+T4+T5 on top of R5's T1+T2):
//   - 4 phases per K-tile, 16 MFMA each (2 m-frags x 4 n x 2 k-slices);
//     b-frags register-hoisted at phase 1 (B LDS halves dead afterwards).
//   - stage stream 3 half-tiles ahead; per tile t stages {t+1:A1, t+2:B0,
//     t+2:B1} in phases 1-3 and t+2:A0 AFTER phase 4's end barrier (A
//     halves are read in every phase; the barrier proves all reads serviced
//     before the overwriting DMA can land).
//   - K-tile fence: s_waitcnt vmcnt(6) + s_barrier (never 0 until tail) ->
//     guarantees tile t+1 fully in LDS while 3 newest halves stay in flight.
//   - raw s_barrier (no implicit drain) + sched_barrier(0) pins (rule #18).
// T2 swizzle (proven 0-conflict in R5): stored chunk j of row r holds source
// chunk j ^ (r&7); ds_read XORs the same. T1: grid 256, xcd = bid&7 = z&7.
// C/D map: col=lane&15, row=(lane>>4)*4+reg.
// ---------------------------------------------------------------------------
template <int MB, bool FIRST>
__device__ __forceinline__ void phase_load(int wm, int wn, int l,
    const u16* ASp, const u16* BSp, f16x8 (&bfr)[4][2], f16x8 (&afr)[2][2]) {
  if constexpr (FIRST) {
#pragma unroll
    for (int n = 0; n < 4; n++) {
      int row = wn * 64 + n * 16 + (l & 15);
#pragma unroll
      for (int ks = 0; ks < 2; ks++) {
        int cjs = (ks * 4 + (l >> 4)) ^ (row & 7);
        bfr[n][ks] = *(const f16x8*)&BSp[row * 64 + cjs * 8];
      }
    }
  }
#pragma unroll
  for (int mm = 0; mm < 2; mm++) {
    int row = wm * 128 + (MB + mm) * 16 + (l & 15);
#pragma unroll
    for (int ks = 0; ks < 2; ks++) {
      int cjs = (ks * 4 + (l >> 4)) ^ (row & 7);
      afr[mm][ks] = *(const f16x8*)&ASp[row * 64 + cjs * 8];
    }
  }
}

template <int MB>
__device__ __forceinline__ void phase_fma(f16x8 (&bfr)[4][2], f16x8 (&afr)[2][2],
                                          f32x4 (&acc)[8][4]) {
  __builtin_amdgcn_s_setprio(1);
#pragma unroll
  for (int n = 0; n < 4; n++) {
#pragma unroll
    for (int mm = 0; mm < 2; mm++) {
      acc[MB + mm][n] = __builtin_amdgcn_mfma_f32_16x16x32_f16(
          afr[mm][0], bfr[n][0], acc[MB + mm][n], 0, 0, 0);
      acc[MB + mm][n] = __builtin_amdgcn_mfma_f32_16x16x32_f16(
          afr[mm][1], bfr[n][1], acc[MB + mm][n], 0, 0, 0);
    }
  }
  __builtin_amdgcn_s_setprio(0);
}

#define SCHED0 __builtin_amdgcn_sched_barrier(0)
#define BARRIER() do { SCHED0; __builtin_amdgcn_s_barrier(); SCHED0; } while (0)

__global__ __launch_bounds__(512, 2) void gemm8(const u16* __restrict__ A0,
    const u16* __restrict__ B0, u16* __restrict__ C0,
    const float* __restrict__ colscale) {
  __shared__ __align__(16) u16 AS[2][256 * 64];
  __shared__ __align__(16) u16 BS[2][256 * 64];
  int t = threadIdx.x;
  int w = t >> 6, l = t & 63;
  int wm = w >> 2, wn = w & 3;
  int bid = blockIdx.x;
  int xcd = bid & 7, rr = bid >> 3;        // rr 0..31
  int z = ((rr >> 4) << 3) | xcd;          // each XCD owns z = {xcd, xcd+8}
  int ti = rr & 15, by = ti >> 2, bx = ti & 3;
  const u16* Ag = A0 + (size_t)z * (1024 * 1024) + (size_t)by * 256 * 1024;
  const u16* Bg = B0 + (size_t)z * (1024 * 1024) + (size_t)bx * 256 * 1024;

  f32x4 acc[8][4];
#pragma unroll
  for (int m = 0; m < 8; m++)
#pragma unroll
    for (int n = 0; n < 4; n++) {
      f32x4 zz = {0.f, 0.f, 0.f, 0.f};
      acc[m][n] = zz;
    }
  f16x8 bfr[4][2];

  // stage one 128x64 half-tile (2 x gload16/thread), pre-swizzled source
  auto stageH = [&](u16* lds, const u16* g, int half, int k0) {
#pragma unroll
    for (int i = 0; i < 2; i++) {
      int cid = i * 512 + t;
      int r = cid >> 3, cj = cid & 7;
      gload16(g + (size_t)(half * 128 + r) * 1024 + k0 + ((cj ^ (r & 7)) * 8),
              lds + (half * 128 + r) * 64 + cj * 8);
    }
  };

  // prologue: tile0 {B0,B1,A0,A1} + tile1 {B0,B1,A0} = 7 halves, 14 loads
  stageH(BS[0], Bg, 0, 0);
  stageH(BS[0], Bg, 1, 0);
  stageH(AS[0], Ag, 0, 0);
  stageH(AS[0], Ag, 1, 0);
  stageH(BS[1], Bg, 0, 64);
  stageH(BS[1], Bg, 1, 64);
  stageH(AS[1], Ag, 0, 64);
  asm volatile("s_waitcnt vmcnt(6)" ::: "memory");  // tile0 landed
  BARRIER();

  for (int kt = 0; kt < 16; kt++) {
    int pb = kt & 1;
    const u16* ASp = AS[pb];
    const u16* BSp = BS[pb];
    int kN1 = (kt + 1) * 64, kN2 = (kt + 2) * 64;
    f16x8 afr[2][2];
    // phase 1: all b-frags + a m0,m1; stage (t+1):A1 (other buffer)
    phase_load<0, true>(wm, wn, l, ASp, BSp, bfr, afr);
    if (kt < 15) stageH(AS[1 - pb], Ag, 1, kN1);
    BARRIER();
    phase_fma<0>(bfr, afr, acc);
    BARRIER();
    // phase 2: a m2,m3; stage (t+2):B0 (this buffer's B dead since phase 1)
    phase_load<2, false>(wm, wn, l, ASp, BSp, bfr, afr);
    if (kt < 14) stageH(BS[pb], Bg, 0, kN2);
    BARRIER();
    phase_fma<2>(bfr, afr, acc);
    BARRIER();
    // phase 3: a m4,m5; stage (t+2):B1
    phase_load<4, false>(wm, wn, l, ASp, BSp, bfr, afr);
    if (kt < 14) stageH(BS[pb], Bg, 1, kN2);
    BARRIER();
    phase_fma<4>(bfr, afr, acc);
    BARRIER();
    // phase 4: a m6,m7; no stage (A halves still being read)
    phase_load<6, false>(wm, wn, l, ASp, BSp, bfr, afr);
    BARRIER();
    phase_fma<6>(bfr, afr, acc);
    BARRIER();
    // post-phase-4: all A reads of tile kt proven serviced -> safe to
    // overwrite this buffer's A0 with (t+2):A0. Then the K-tile fence.
    if (kt < 14) stageH(AS[pb], Ag, 0, kN2);
    if (kt < 15) {
      if (kt == 14) asm volatile("s_waitcnt vmcnt(0)" ::: "memory");
      else          asm volatile("s_waitcnt vmcnt(6)" ::: "memory");
      BARRIER();
    }
  }

  u16* Cp = C0 + (size_t)z * (1024 * 1024);
  const float* csz = colscale + (size_t)z * 1024;
  int rbase = by * 256 + wm * 128 + (l >> 4) * 4;
  int cbase = bx * 256 + wn * 64 + (l & 15);
  float sc[4];
#pragma unroll
  for (int n = 0; n < 4; n++) sc[n] = csz[cbase + n * 16];
#pragma unroll
  for (int m = 0; m < 8; m++)
#pragma unroll
    for (int n = 0; n < 4; n++)
#pragma unroll
      for (int j = 0; j < 4; j++)
        Cp[(size_t)(rbase + m * 16 + j) * 1024 + cbase + n * 16] =
            f2h(acc[m][n][j] * sc[n]);
}

// ---------------------------------------------------------------------------
// oproj: partial[b][kc][o][n] = sum_{c in kc-chunk} att[b][c][n]*w_out[o][c].
// ---------------------------------------------------------------------------
__global__ __launch_bounds__(256) void oproj(const u16* __restrict__ att,
    const float* __restrict__ wout, float* __restrict__ partial) {
  __shared__ __align__(16) float wS[128 * 20];
  int t = threadIdx.x;
  int kc = blockIdx.x, og = blockIdx.y, b = blockIdx.z;
  for (int i = t; i < 128 * 16; i += 256) {
    int cc = i & 127, oo = i >> 7;
    wS[cc * 20 + oo] = wout[(size_t)(og * 16 + oo) * HID + kc * 128 + cc];
  }
  __syncthreads();
  f32x4 acc[16];
#pragma unroll
  for (int o = 0; o < 16; o++) {
    f32x4 zz = {0.f, 0.f, 0.f, 0.f};
    acc[o] = zz;
  }
  const u16* X = att + ((size_t)b * HID + kc * 128) * NSP + t * 4;
#pragma unroll 4
  for (int cc = 0; cc < 128; cc++) {
    u16x4 xr = *(const u16x4*)(X + (size_t)cc * NSP);
    f32x4 x = {h2f(xr[0]), h2f(xr[1]), h2f(xr[2]), h2f(xr[3])};
    const f32x4* wv = (const f32x4*)&wS[cc * 20];
#pragma unroll
    for (int g = 0; g < 4; g++) {
      f32x4 w4 = wv[g];
      acc[g * 4 + 0] += w4[0] * x;
      acc[g * 4 + 1] += w4[1] * x;
      acc[g * 4 + 2] += w4[2] * x;
      acc[g * 4 + 3] += w4[3] * x;
    }
  }
#pragma unroll
  for (int o = 0; o < 16; o++)
    *(f32x4*)&partial[(((size_t)b * 32 + kc) * 32 + og * 16 + o) * NSP + t * 4] = acc[o];
}

// ---------------------------------------------------------------------------
// reduce_stats: one thread per output element; 32 kc-partials in independent
// registers (32 loads in flight). Grid 512 x 256.
// ---------------------------------------------------------------------------
__global__ __launch_bounds__(256) void reduce_stats(const float* __restrict__ partial,
    const float* __restrict__ bout, float* __restrict__ fin,
    float* __restrict__ stats) {
  int t = threadIdx.x;
  int gid = blockIdx.x * 256 + t;  // 131072 = 4b * 32o * 1024n
  int n = gid & 1023;
  int o = (gid >> 10) & 31;
  int b = gid >> 15;
  const float* p = partial + ((size_t)b * 32 * 32 + o) * NSP + n;
  float v[32];
#pragma unroll
  for (int kc = 0; kc < 32; kc++) v[kc] = p[(size_t)kc * 32 * NSP];
  float s = bout[o];
#pragma unroll
  for (int kc = 0; kc < 32; kc++) s += v[kc];
  fin[((size_t)b * 32 + o) * NSP + n] = s;
  float s1 = s, s2 = s * s;
#pragma unroll
  for (int off = 32; off > 0; off >>= 1) {
    s1 += __shfl_xor(s1, off);
    s2 += __shfl_xor(s2, off);
  }
  __shared__ float r1[4], r2[4];
  int wid = t >> 6;
  if ((t & 63) == 0) { r1[wid] = s1; r2[wid] = s2; }
  __syncthreads();
  if (t == 0) {
    stats[blockIdx.x * 2 + 0] = r1[0] + r1[1] + r1[2] + r1[3];
    stats[blockIdx.x * 2 + 1] = r2[0] + r2[1] + r2[2] + r2[3];
  }
}

// ---------------------------------------------------------------------------
// gn_norm: GroupNorm(1, C) per batch; aggregates 128 per-block stats.
// ---------------------------------------------------------------------------
__global__ __launch_bounds__(256) void gn_norm(const float* __restrict__ fin,
    const float* __restrict__ stats, const float* __restrict__ gamma,
    const float* __restrict__ beta, float* __restrict__ out) {
  int t = threadIdx.x;
  int nc = blockIdx.x, b = blockIdx.y;
  float s1 = 0.f, s2 = 0.f;
  for (int i = 0; i < 128; i++) {
    s1 += stats[(b * 128 + i) * 2 + 0];
    s2 += stats[(b * 128 + i) * 2 + 1];
  }
  const float inv_n = 1.0f / 32768.0f;
  float mean = s1 * inv_n;
  float var = s2 * inv_n - mean * mean;
  float rstd = rsqrtf(var + 1e-5f);
  int nl = t & 63, oq = t >> 6;
  int n = nc * 64 + nl;
#pragma unroll
  for (int oo = 0; oo < 8; oo++) {
    int o = oq * 8 + oo;
    float v = fin[((size_t)b * 32 + o) * NSP + n];
    out[((size_t)b * 32 + o) * NSP + n] = (v - mean) * rstd * gamma[o] + beta[o];
  }
}

// ---------------------------------------------------------------------------
extern "C" void kernel_launch(void* const* d_in, const int* in_sizes, int n_in,
                              void* d_out, int out_size, void* d_ws, size_t ws_size,
                              hipStream_t stream) {
  (void)in_sizes; (void)n_in; (void)out_size; (void)ws_size;
  const float* img   = (const float*)d_in[0];
  const float* wqkv  = (const float*)d_in[1];
  const float* bqkv  = (const float*)d_in[2];
  const float* wout  = (const float*)d_in[3];
  const float* bout  = (const float*)d_in[4];
  const float* gamma = (const float*)d_in[5];
  const float* beta  = (const float*)d_in[6];
  char* ws = (char*)d_ws;
  u16*   v       = (u16*)(ws + 0);            // 33,554,432
  u16*   att     = (u16*)(ws + 0);            // alias of v (dead after GEMM1)
  u16*   kexp    = (u16*)(ws + 33554432);     // 33,554,432
  u16*   qtexp   = (u16*)(ws + 67108864);     // 33,554,432
  u16*   ctx     = (u16*)(ws + 100663296);    // 33,554,432
  float* stats   = (float*)(ws + 100663296);  // 4,096 (alias, post-GEMM2)
  float* partial = (float*)(ws + 134217728);  // 16,777,216 (oproj)
  float* kinv    = (float*)(ws + 134217728);  // 65,536 (pre-oproj)
  float* qinv    = (float*)(ws + 134283264);  // 65,536 (pre-oproj)
  float* fin     = (float*)(ws + 150994944);  // 524,288
  float* out = (float*)d_out;

  conv_kv<2 * HID, false><<<dim3(64, 4, 4), 256, 0, stream>>>(img, wqkv, bqkv, v);
  conv_kv<1 * HID, true ><<<dim3(64, 4, 4), 256, 0, stream>>>(img, wqkv, bqkv, kexp);
  conv_q<<<dim3(16, 4, 16), 256, 0, stream>>>(img, wqkv, bqkv, qtexp);
  rowinv<<<dim3(8192), 256, 0, stream>>>(kexp, qtexp, kinv, qinv);
  // ctx[e][d] = (sum_n V[e,n] * Kexp[d,n]) * kinv[d]
  gemm8<<<dim3(256), 512, 0, stream>>>(v, kexp, ctx, kinv);
  // att[e][n] = (sum_d ctx[e,d] * qtexp[n,d]) * qinv[n]
  gemm8<<<dim3(256), 512, 0, stream>>>(ctx, qtexp, att, qinv);
  oproj<<<dim3(32, 2, 4), 256, 0, stream>>>(att, wout, partial);
  reduce_stats<<<dim3(512), 256, 0, stream>>>(partial, bout, fin, stats);
  gn_norm<<<dim3(16, 4), 256, 0, stream>>>(fin, stats, gamma, beta, out);
}